// Round 1
// baseline (1429.029 us; speedup 1.0000x reference)
//
#include <hip/hip_runtime.h>
#include <hip/hip_bf16.h>

// BasicGCN: out = log_softmax( A @ (relu(A @ x @ W1 + b1) @ W2) + b2 )
// where A is the sym-normalized adjacency with self-loops.
// Strategy: reorder layer1 as (A@x)@W1 (aggregate in input space), layer2 as
// A@(h1@W2) (aggregate in 64-dim output space). CSR built on-device each call.

typedef __bf16 bf16;
typedef bf16 bf16x4 __attribute__((ext_vector_type(4)));
typedef bf16 bf16x8 __attribute__((ext_vector_type(8)));
typedef float f32x4 __attribute__((ext_vector_type(4)));

// ---------------- degree histogram ----------------
__global__ void k_deg(const int* __restrict__ edge, int E, int* __restrict__ deg) {
    int e = blockIdx.x * blockDim.x + threadIdx.x;
    if (e < E) atomicAdd(&deg[edge[E + e]], 1);
}

// ---------------- single-block scan: offsets, cursor, dinv ----------------
__global__ void k_scan(const int* __restrict__ deg, int n, int E,
                       int* __restrict__ off, int* __restrict__ cur,
                       float* __restrict__ dinv) {
    __shared__ int sums[1024];
    int tid = threadIdx.x;
    int chunk = (n + 1023) >> 10;
    int s = tid * chunk;
    int e = s + chunk; if (e > n) e = n; if (s > n) s = n;
    int local = 0;
    for (int i = s; i < e; ++i) local += deg[i];
    sums[tid] = local;
    __syncthreads();
    for (int o = 1; o < 1024; o <<= 1) {
        int v = (tid >= o) ? sums[tid - o] : 0;
        __syncthreads();
        sums[tid] += v;
        __syncthreads();
    }
    int run = sums[tid] - local;  // exclusive prefix
    for (int i = s; i < e; ++i) {
        off[i] = run;
        cur[i] = run;
        dinv[i] = rsqrtf((float)(deg[i] + 1));  // +1 self-loop; always >=1
        run += deg[i];
    }
    if (tid == 1023) off[n] = E;
}

// ---------------- CSR fill ----------------
__global__ void k_csr(const int* __restrict__ edge, int E,
                      const float* __restrict__ dinv,
                      int* __restrict__ cur, int* __restrict__ csr_src,
                      float* __restrict__ csr_w) {
    int e = blockIdx.x * blockDim.x + threadIdx.x;
    if (e >= E) return;
    int s = edge[e], d = edge[E + e];
    int p = atomicAdd(&cur[d], 1);
    csr_src[p] = s;
    csr_w[p] = dinv[s];  // dinv[dst] factored out at node level
}

// ---------------- fp32 -> bf16 convert (vectorized) ----------------
__global__ void k_cvt(const float* __restrict__ x, bf16* __restrict__ xb, int count4) {
    int i = blockIdx.x * blockDim.x + threadIdx.x;
    if (i >= count4) return;
    f32x4 v = ((const f32x4*)x)[i];
    bf16x4 o;
    o[0] = (bf16)v[0]; o[1] = (bf16)v[1]; o[2] = (bf16)v[2]; o[3] = (bf16)v[3];
    ((bf16x4*)xb)[i] = o;
}

// ---------------- W (KxNC fp32) -> Wt (NCxK bf16) ----------------
__global__ void k_wt(const float* __restrict__ W, bf16* __restrict__ Wt, int NC) {
    int nc = blockIdx.x;       // 0..NC-1
    int k = threadIdx.x;       // 0..255
    Wt[nc * 256 + k] = (bf16)W[k * NC + nc];
}

// ---------------- aggregation 1: ax = A @ x   (256-dim, one wave/node) ----------------
__global__ void k_agg1(const bf16* __restrict__ xb, const int* __restrict__ off,
                       const int* __restrict__ csr_src, const float* __restrict__ csr_w,
                       const float* __restrict__ dinv, bf16* __restrict__ ax, int n) {
    int wv = blockIdx.x * (blockDim.x >> 6) + (threadIdx.x >> 6);
    if (wv >= n) return;
    int lane = threadIdx.x & 63;
    int s0 = off[wv], s1 = off[wv + 1];
    float dv = dinv[wv];
    const bf16x4* X = (const bf16x4*)xb;
    bf16x4 xs = X[(size_t)wv * 64 + lane];
    float a0 = dv * (float)xs[0], a1 = dv * (float)xs[1],
          a2 = dv * (float)xs[2], a3 = dv * (float)xs[3];
    for (int e = s0; e < s1; ++e) {
        int s = csr_src[e];
        float w = csr_w[e];
        bf16x4 t = X[(size_t)s * 64 + lane];
        a0 += w * (float)t[0];
        a1 += w * (float)t[1];
        a2 += w * (float)t[2];
        a3 += w * (float)t[3];
    }
    bf16x4 o;
    o[0] = (bf16)(a0 * dv); o[1] = (bf16)(a1 * dv);
    o[2] = (bf16)(a2 * dv); o[3] = (bf16)(a3 * dv);
    ((bf16x4*)ax)[(size_t)wv * 64 + lane] = o;
}

// ---------------- bf16 MFMA GEMM: C[n x NC] = A[n x 256] @ Bt[NC x 256]^T ----------------
// 64x64 block tile, BK=32, 4 waves each 32x32 (2x2 MFMA 16x16x32).
// LDS in fragment order: [tile16group][lane][8 bf16] -> all LDS ops are b128.
template <bool BIAS_RELU>
__global__ __launch_bounds__(256) void k_gemm(const bf16* __restrict__ A,
                                              const bf16* __restrict__ Bt,
                                              const float* __restrict__ bias,
                                              bf16* __restrict__ C, int n, int NC) {
    __shared__ __align__(16) bf16 As[4 * 64 * 8];
    __shared__ __align__(16) bf16 Bs[4 * 64 * 8];
    int tid = threadIdx.x;
    int bm = blockIdx.x * 64;
    int bn = blockIdx.y * 64;
    int w = tid >> 6, lane = tid & 63;
    int wm = w >> 1, wn = w & 1;

    // staging map: thread -> (row r of tile, k-chunk cq)
    int r = tid >> 2;
    int cq = tid & 3;
    int lds_idx = (((r >> 4) * 64) + cq * 16 + (r & 15)) * 8;  // element index
    int arow = bm + r; if (arow > n - 1) arow = n - 1;
    int brow = bn + r;

    f32x4 acc[2][2] = {};

    for (int k0 = 0; k0 < 256; k0 += 32) {
        __syncthreads();
        uint4 av = *(const uint4*)(A + (size_t)arow * 256 + k0 + cq * 8);
        uint4 bv = *(const uint4*)(Bt + (size_t)brow * 256 + k0 + cq * 8);
        *(uint4*)(As + lds_idx) = av;
        *(uint4*)(Bs + lds_idx) = bv;
        __syncthreads();
#pragma unroll
        for (int i = 0; i < 2; ++i) {
            bf16x8 af = *(const bf16x8*)(As + ((wm * 2 + i) * 64 + lane) * 8);
#pragma unroll
            for (int j = 0; j < 2; ++j) {
                bf16x8 bfr = *(const bf16x8*)(Bs + ((wn * 2 + j) * 64 + lane) * 8);
                acc[i][j] = __builtin_amdgcn_mfma_f32_16x16x32_bf16(af, bfr, acc[i][j], 0, 0, 0);
            }
        }
    }

    // epilogue: D row=(lane>>4)*4+rr, col=lane&15  [verified layout]
    int colb = lane & 15, rowq = lane >> 4;
#pragma unroll
    for (int i = 0; i < 2; ++i) {
#pragma unroll
        for (int j = 0; j < 2; ++j) {
            int col = bn + wn * 32 + j * 16 + colb;
#pragma unroll
            for (int rr = 0; rr < 4; ++rr) {
                int row = bm + wm * 32 + i * 16 + rowq * 4 + rr;
                if (row < n) {
                    float v = acc[i][j][rr];
                    if constexpr (BIAS_RELU) {
                        v += bias[col];
                        v = v > 0.0f ? v : 0.0f;
                    }
                    C[(size_t)row * NC + col] = (bf16)v;
                }
            }
        }
    }
}

// ---------------- aggregation 2 + bias + log_softmax (one wave/node, lane=col) ----------------
__global__ void k_agg2(const bf16* __restrict__ t, const int* __restrict__ off,
                       const int* __restrict__ csr_src, const float* __restrict__ csr_w,
                       const float* __restrict__ dinv, const float* __restrict__ b2,
                       float* __restrict__ out, int n) {
    int wv = blockIdx.x * (blockDim.x >> 6) + (threadIdx.x >> 6);
    if (wv >= n) return;
    int lane = threadIdx.x & 63;
    int s0 = off[wv], s1 = off[wv + 1];
    float dv = dinv[wv];
    float a = dv * (float)t[(size_t)wv * 64 + lane];
    for (int e = s0; e < s1; ++e) {
        int s = csr_src[e];
        float w = csr_w[e];
        a += w * (float)t[(size_t)s * 64 + lane];
    }
    a = a * dv + b2[lane];
    // log_softmax across the 64 lanes
    float m = a;
    for (int o = 32; o > 0; o >>= 1) m = fmaxf(m, __shfl_xor(m, o));
    float ex = __expf(a - m);
    float ssum = ex;
    for (int o = 32; o > 0; o >>= 1) ssum += __shfl_xor(ssum, o);
    out[(size_t)wv * 64 + lane] = a - m - __logf(ssum);
}

extern "C" void kernel_launch(void* const* d_in, const int* in_sizes, int n_in,
                              void* d_out, int out_size, void* d_ws, size_t ws_size,
                              hipStream_t stream) {
    const float* x   = (const float*)d_in[0];
    const int*  edge = (const int*)d_in[1];
    const float* W1  = (const float*)d_in[2];
    const float* b1  = (const float*)d_in[3];
    const float* W2  = (const float*)d_in[4];
    const float* b2  = (const float*)d_in[5];
    float* out = (float*)d_out;

    int n = in_sizes[0] / 256;   // 100000
    int E = in_sizes[1] / 2;     // 3200000

    char* ws = (char*)d_ws;
    auto alloc = [&](size_t bytes) -> char* {
        char* p = ws;
        ws += (bytes + 255) & ~(size_t)255;
        return p;
    };
    int*   deg     = (int*)alloc((size_t)n * 4);
    float* dinv    = (float*)alloc((size_t)n * 4);
    int*   off     = (int*)alloc((size_t)(n + 1) * 4);
    int*   cur     = (int*)alloc((size_t)n * 4);
    int*   csr_src = (int*)alloc((size_t)E * 4);
    float* csr_w   = (float*)alloc((size_t)E * 4);
    bf16*  xb      = (bf16*)alloc((size_t)n * 256 * 2);
    bf16*  ax      = (bf16*)alloc((size_t)n * 256 * 2);
    bf16*  tb      = (bf16*)alloc((size_t)n * 64 * 2);
    bf16*  W1t     = (bf16*)alloc(256 * 256 * 2);
    bf16*  W2t     = (bf16*)alloc(64 * 256 * 2);
    bf16*  h1      = xb;  // xb is dead after agg1; reuse for h1

    hipMemsetAsync(deg, 0, (size_t)n * 4, stream);
    k_deg<<<(E + 255) / 256, 256, 0, stream>>>(edge, E, deg);
    k_scan<<<1, 1024, 0, stream>>>(deg, n, E, off, cur, dinv);
    k_csr<<<(E + 255) / 256, 256, 0, stream>>>(edge, E, dinv, cur, csr_src, csr_w);
    k_cvt<<<(n * 64 + 255) / 256, 256, 0, stream>>>(x, xb, n * 64);
    k_wt<<<256, 256, 0, stream>>>(W1, W1t, 256);
    k_wt<<<64, 256, 0, stream>>>(W2, W2t, 64);

    k_agg1<<<(n + 3) / 4, 256, 0, stream>>>(xb, off, csr_src, csr_w, dinv, ax, n);

    dim3 g1((n + 63) / 64, 4);
    k_gemm<true><<<g1, 256, 0, stream>>>(ax, W1t, b1, h1, n, 256);
    dim3 g2((n + 63) / 64, 1);
    k_gemm<false><<<g2, 256, 0, stream>>>(h1, W2t, nullptr, tb, n, 64);

    k_agg2<<<(n + 3) / 4, 256, 0, stream>>>(tb, off, csr_src, csr_w, dinv, b2, out, n);
}

// Round 2
// 823.112 us; speedup vs baseline: 1.7361x; 1.7361x over previous
//
#include <hip/hip_runtime.h>
#include <hip/hip_bf16.h>

// BasicGCN: out = log_softmax( A @ (relu(A @ x @ W1 + b1) @ W2) + b2 )
// A = sym-normalized adjacency with self-loops.
// Layer1 computed as (A@x)@W1 ; layer2 as A@(h1@W2) (64-dim aggregation).
// R2: MLP-focused agg kernels (unrolled gathers, 2 nodes/wave), fused (src,w)
// int2 CSR payload, parallel 3-kernel scan.

typedef __bf16 bf16;
typedef bf16 bf16x2 __attribute__((ext_vector_type(2)));
typedef bf16 bf16x4 __attribute__((ext_vector_type(4)));
typedef bf16 bf16x8 __attribute__((ext_vector_type(8)));
typedef float f32x4 __attribute__((ext_vector_type(4)));

// ---------------- degree histogram ----------------
__global__ void k_deg(const int* __restrict__ edge, int E, int* __restrict__ deg) {
    int e = blockIdx.x * blockDim.x + threadIdx.x;
    if (e < E) atomicAdd(&deg[edge[E + e]], 1);
}

// ---------------- parallel scan (3 tiny kernels over 1024-node chunks) ----------------
__global__ void k_scan1(const int* __restrict__ deg, int n, int* __restrict__ bsum) {
    __shared__ int red[256];
    int base = blockIdx.x * 1024;
    int tid = threadIdx.x;
    int s = 0;
#pragma unroll
    for (int j = 0; j < 4; ++j) {
        int i = base + j * 256 + tid;
        if (i < n) s += deg[i];
    }
    red[tid] = s;
    __syncthreads();
    for (int o = 128; o > 0; o >>= 1) {
        if (tid < o) red[tid] += red[tid + o];
        __syncthreads();
    }
    if (tid == 0) bsum[blockIdx.x] = red[0];
}

__global__ void k_scan2(int* __restrict__ bsum, int nb, int E, int* __restrict__ off, int n) {
    if (threadIdx.x == 0) {
        int run = 0;
        for (int b = 0; b < nb; ++b) { int v = bsum[b]; bsum[b] = run; run += v; }
        off[n] = E;
    }
}

__global__ void k_scan3(const int* __restrict__ deg, int n, const int* __restrict__ bbase,
                        int* __restrict__ off, int* __restrict__ cur, float* __restrict__ dinv) {
    __shared__ int red[256];
    int base = blockIdx.x * 1024;
    int tid = threadIdx.x;
    int d[4], t = 0;
#pragma unroll
    for (int j = 0; j < 4; ++j) {
        int i = base + tid * 4 + j;
        d[j] = (i < n) ? deg[i] : 0;
        t += d[j];
    }
    red[tid] = t;
    __syncthreads();
    for (int o = 1; o < 256; o <<= 1) {
        int v = (tid >= o) ? red[tid - o] : 0;
        __syncthreads();
        red[tid] += v;
        __syncthreads();
    }
    int run = bbase[blockIdx.x] + red[tid] - t;  // exclusive prefix
#pragma unroll
    for (int j = 0; j < 4; ++j) {
        int i = base + tid * 4 + j;
        if (i < n) {
            off[i] = run;
            cur[i] = run;
            dinv[i] = rsqrtf((float)(d[j] + 1));  // +1 self-loop
            run += d[j];
        }
    }
}

// ---------------- CSR fill: one 8B (src, w) store per edge ----------------
__global__ void k_csr(const int* __restrict__ edge, int E, const float* __restrict__ dinv,
                      int* __restrict__ cur, int2* __restrict__ pair) {
    int e = blockIdx.x * blockDim.x + threadIdx.x;
    if (e >= E) return;
    int s = edge[e], d = edge[E + e];
    int p = atomicAdd(&cur[d], 1);
    pair[p] = make_int2(s, __float_as_int(dinv[s]));
}

// ---------------- fp32 -> bf16 convert ----------------
__global__ void k_cvt(const float* __restrict__ x, bf16* __restrict__ xb, int count4) {
    int i = blockIdx.x * blockDim.x + threadIdx.x;
    if (i >= count4) return;
    f32x4 v = ((const f32x4*)x)[i];
    bf16x4 o;
    o[0] = (bf16)v[0]; o[1] = (bf16)v[1]; o[2] = (bf16)v[2]; o[3] = (bf16)v[3];
    ((bf16x4*)xb)[i] = o;
}

// ---------------- W (KxNC fp32) -> Wt (NCxK bf16) ----------------
__global__ void k_wt(const float* __restrict__ W, bf16* __restrict__ Wt, int NC) {
    int nc = blockIdx.x;
    int k = threadIdx.x;
    Wt[nc * 256 + k] = (bf16)W[k * NC + nc];
}

// ---------------- agg1: ax = A @ x (256-dim). 2 nodes/wave, 16B/lane, unroll 4 ----------------
__global__ __launch_bounds__(256) void k_agg1(const bf16* __restrict__ xb,
                                              const int* __restrict__ off,
                                              const int2* __restrict__ pair,
                                              const float* __restrict__ dinv,
                                              bf16* __restrict__ ax, int n) {
    int wv = blockIdx.x * 4 + (threadIdx.x >> 6);
    int lane = threadIdx.x & 63;
    int node = wv * 2 + (lane >> 5);
    int l32 = lane & 31;
    if (node >= n) return;
    int s0 = off[node], s1 = off[node + 1];
    float dv = dinv[node];
    const bf16x8* X = (const bf16x8*)xb;
    bf16x8 xs = X[(size_t)node * 32 + l32];
    float a[8];
#pragma unroll
    for (int j = 0; j < 8; ++j) a[j] = dv * (float)xs[j];
    int e = s0;
    for (; e + 4 <= s1; e += 4) {
        int2 p0 = pair[e], p1 = pair[e + 1], p2 = pair[e + 2], p3 = pair[e + 3];
        bf16x8 t0 = X[(size_t)p0.x * 32 + l32];
        bf16x8 t1 = X[(size_t)p1.x * 32 + l32];
        bf16x8 t2 = X[(size_t)p2.x * 32 + l32];
        bf16x8 t3 = X[(size_t)p3.x * 32 + l32];
        float w0 = __int_as_float(p0.y), w1 = __int_as_float(p1.y);
        float w2 = __int_as_float(p2.y), w3 = __int_as_float(p3.y);
#pragma unroll
        for (int j = 0; j < 8; ++j)
            a[j] += w0 * (float)t0[j] + w1 * (float)t1[j] + w2 * (float)t2[j] + w3 * (float)t3[j];
    }
    for (; e < s1; ++e) {
        int2 p = pair[e];
        bf16x8 t = X[(size_t)p.x * 32 + l32];
        float w = __int_as_float(p.y);
#pragma unroll
        for (int j = 0; j < 8; ++j) a[j] += w * (float)t[j];
    }
    bf16x8 o;
#pragma unroll
    for (int j = 0; j < 8; ++j) o[j] = (bf16)(a[j] * dv);
    ((bf16x8*)ax)[(size_t)node * 32 + l32] = o;
}

// ---------------- bf16 MFMA GEMM: C[n x NC] = A[n x 256] @ Bt[NC x 256]^T ----------------
template <bool BIAS_RELU>
__global__ __launch_bounds__(256) void k_gemm(const bf16* __restrict__ A,
                                              const bf16* __restrict__ Bt,
                                              const float* __restrict__ bias,
                                              bf16* __restrict__ C, int n, int NC) {
    __shared__ __align__(16) bf16 As[4 * 64 * 8];
    __shared__ __align__(16) bf16 Bs[4 * 64 * 8];
    int tid = threadIdx.x;
    int bm = blockIdx.x * 64;
    int bn = blockIdx.y * 64;
    int w = tid >> 6, lane = tid & 63;
    int wm = w >> 1, wn = w & 1;

    int r = tid >> 2;
    int cq = tid & 3;
    int lds_idx = (((r >> 4) * 64) + cq * 16 + (r & 15)) * 8;
    int arow = bm + r; if (arow > n - 1) arow = n - 1;
    int brow = bn + r;

    f32x4 acc[2][2] = {};

    for (int k0 = 0; k0 < 256; k0 += 32) {
        __syncthreads();
        uint4 av = *(const uint4*)(A + (size_t)arow * 256 + k0 + cq * 8);
        uint4 bv = *(const uint4*)(Bt + (size_t)brow * 256 + k0 + cq * 8);
        *(uint4*)(As + lds_idx) = av;
        *(uint4*)(Bs + lds_idx) = bv;
        __syncthreads();
#pragma unroll
        for (int i = 0; i < 2; ++i) {
            bf16x8 af = *(const bf16x8*)(As + ((wm * 2 + i) * 64 + lane) * 8);
#pragma unroll
            for (int j = 0; j < 2; ++j) {
                bf16x8 bfr = *(const bf16x8*)(Bs + ((wn * 2 + j) * 64 + lane) * 8);
                acc[i][j] = __builtin_amdgcn_mfma_f32_16x16x32_bf16(af, bfr, acc[i][j], 0, 0, 0);
            }
        }
    }

    int colb = lane & 15, rowq = lane >> 4;
#pragma unroll
    for (int i = 0; i < 2; ++i) {
#pragma unroll
        for (int j = 0; j < 2; ++j) {
            int col = bn + wn * 32 + j * 16 + colb;
#pragma unroll
            for (int rr = 0; rr < 4; ++rr) {
                int row = bm + wm * 32 + i * 16 + rowq * 4 + rr;
                if (row < n) {
                    float v = acc[i][j][rr];
                    if constexpr (BIAS_RELU) {
                        v += bias[col];
                        v = v > 0.0f ? v : 0.0f;
                    }
                    C[(size_t)row * NC + col] = (bf16)v;
                }
            }
        }
    }
}

// ---------------- agg2 + bias + log_softmax. 2 nodes/wave, bf16x2/lane, unroll 8 ----------------
__global__ __launch_bounds__(256) void k_agg2(const bf16* __restrict__ t,
                                              const int* __restrict__ off,
                                              const int2* __restrict__ pair,
                                              const float* __restrict__ dinv,
                                              const float* __restrict__ b2,
                                              float* __restrict__ out, int n) {
    int wv = blockIdx.x * 4 + (threadIdx.x >> 6);
    int lane = threadIdx.x & 63;
    int node = wv * 2 + (lane >> 5);
    int l32 = lane & 31;
    if (node >= n) return;
    int s0 = off[node], s1 = off[node + 1];
    float dv = dinv[node];
    const bf16x2* T = (const bf16x2*)t;
    bf16x2 ts = T[(size_t)node * 32 + l32];
    float a0 = dv * (float)ts[0], a1 = dv * (float)ts[1];
    int e = s0;
    for (; e + 8 <= s1; e += 8) {
        int2 p[8];
#pragma unroll
        for (int q = 0; q < 8; ++q) p[q] = pair[e + q];
        bf16x2 tv[8];
#pragma unroll
        for (int q = 0; q < 8; ++q) tv[q] = T[(size_t)p[q].x * 32 + l32];
#pragma unroll
        for (int q = 0; q < 8; ++q) {
            float w = __int_as_float(p[q].y);
            a0 += w * (float)tv[q][0];
            a1 += w * (float)tv[q][1];
        }
    }
    for (; e < s1; ++e) {
        int2 p = pair[e];
        bf16x2 tv = T[(size_t)p.x * 32 + l32];
        float w = __int_as_float(p.y);
        a0 += w * (float)tv[0];
        a1 += w * (float)tv[1];
    }
    a0 = a0 * dv + b2[l32 * 2];
    a1 = a1 * dv + b2[l32 * 2 + 1];
    // log_softmax over the 64 cols held by this 32-lane half (xor<=16 stays in half)
    float m = fmaxf(a0, a1);
    for (int o = 16; o > 0; o >>= 1) m = fmaxf(m, __shfl_xor(m, o));
    float s = __expf(a0 - m) + __expf(a1 - m);
    for (int o = 16; o > 0; o >>= 1) s += __shfl_xor(s, o);
    float ls = __logf(s);
    float2 ov = make_float2(a0 - m - ls, a1 - m - ls);
    ((float2*)out)[(size_t)node * 32 + l32] = ov;
}

extern "C" void kernel_launch(void* const* d_in, const int* in_sizes, int n_in,
                              void* d_out, int out_size, void* d_ws, size_t ws_size,
                              hipStream_t stream) {
    const float* x   = (const float*)d_in[0];
    const int*  edge = (const int*)d_in[1];
    const float* W1  = (const float*)d_in[2];
    const float* b1  = (const float*)d_in[3];
    const float* W2  = (const float*)d_in[4];
    const float* b2  = (const float*)d_in[5];
    float* out = (float*)d_out;

    int n = in_sizes[0] / 256;   // 100000
    int E = in_sizes[1] / 2;     // 3200000
    int nb = (n + 1023) / 1024;  // scan chunks

    char* ws = (char*)d_ws;
    auto alloc = [&](size_t bytes) -> char* {
        char* p = ws;
        ws += (bytes + 255) & ~(size_t)255;
        return p;
    };
    int*   deg  = (int*)alloc((size_t)n * 4);
    float* dinv = (float*)alloc((size_t)n * 4);
    int*   off  = (int*)alloc((size_t)(n + 1) * 4);
    int*   cur  = (int*)alloc((size_t)n * 4);
    int*   bsum = (int*)alloc((size_t)nb * 4);
    int2*  pair = (int2*)alloc((size_t)E * 8);
    bf16*  xb   = (bf16*)alloc((size_t)n * 256 * 2);
    bf16*  ax   = (bf16*)alloc((size_t)n * 256 * 2);
    bf16*  tb   = (bf16*)alloc((size_t)n * 64 * 2);
    bf16*  W1t  = (bf16*)alloc(256 * 256 * 2);
    bf16*  W2t  = (bf16*)alloc(64 * 256 * 2);
    bf16*  h1   = xb;  // xb dead after agg1; reuse for h1

    hipMemsetAsync(deg, 0, (size_t)n * 4, stream);
    k_deg<<<(E + 255) / 256, 256, 0, stream>>>(edge, E, deg);
    k_scan1<<<nb, 256, 0, stream>>>(deg, n, bsum);
    k_scan2<<<1, 64, 0, stream>>>(bsum, nb, E, off, n);
    k_scan3<<<nb, 256, 0, stream>>>(deg, n, bsum, off, cur, dinv);
    k_csr<<<(E + 255) / 256, 256, 0, stream>>>(edge, E, dinv, cur, pair);
    k_cvt<<<(n * 64 + 255) / 256, 256, 0, stream>>>(x, xb, n * 64);
    k_wt<<<256, 256, 0, stream>>>(W1, W1t, 256);
    k_wt<<<64, 256, 0, stream>>>(W2, W2t, 64);

    k_agg1<<<(n + 7) / 8, 256, 0, stream>>>(xb, off, pair, dinv, ax, n);

    dim3 g1((n + 63) / 64, 4);
    k_gemm<true><<<g1, 256, 0, stream>>>(ax, W1t, b1, h1, n, 256);
    dim3 g2((n + 63) / 64, 1);
    k_gemm<false><<<g2, 256, 0, stream>>>(h1, W2t, nullptr, tb, n, 64);

    k_agg2<<<(n + 7) / 8, 256, 0, stream>>>(tb, off, pair, dinv, b2, out, n);
}

// Round 3
// 755.287 us; speedup vs baseline: 1.8920x; 1.0898x over previous
//
#include <hip/hip_runtime.h>
#include <hip/hip_bf16.h>

// BasicGCN: out = log_softmax( A @ (relu(A @ x @ W1 + b1) @ W2) + b2 )
// A = sym-normalized adjacency with self-loops.
// Layer1 computed as (A@x)@W1 ; layer2 as A@(h1@W2) (64-dim aggregation).
// R3: agg2 8-nodes/wave 16B lanes; csr fill without atomics (rank from deg
// pass); agg1 unroll 8.

typedef __bf16 bf16;
typedef bf16 bf16x2 __attribute__((ext_vector_type(2)));
typedef bf16 bf16x4 __attribute__((ext_vector_type(4)));
typedef bf16 bf16x8 __attribute__((ext_vector_type(8)));
typedef float f32x4 __attribute__((ext_vector_type(4)));

// ---------------- degree histogram + per-edge rank ----------------
__global__ void k_deg(const int* __restrict__ edge, int E, int* __restrict__ deg,
                      int* __restrict__ erank) {
    int e = blockIdx.x * blockDim.x + threadIdx.x;
    if (e < E) erank[e] = atomicAdd(&deg[edge[E + e]], 1);
}

// ---------------- parallel scan (3 tiny kernels over 1024-node chunks) ----------------
__global__ void k_scan1(const int* __restrict__ deg, int n, int* __restrict__ bsum) {
    __shared__ int red[256];
    int base = blockIdx.x * 1024;
    int tid = threadIdx.x;
    int s = 0;
#pragma unroll
    for (int j = 0; j < 4; ++j) {
        int i = base + j * 256 + tid;
        if (i < n) s += deg[i];
    }
    red[tid] = s;
    __syncthreads();
    for (int o = 128; o > 0; o >>= 1) {
        if (tid < o) red[tid] += red[tid + o];
        __syncthreads();
    }
    if (tid == 0) bsum[blockIdx.x] = red[0];
}

__global__ void k_scan2(int* __restrict__ bsum, int nb, int E, int* __restrict__ off, int n) {
    if (threadIdx.x == 0) {
        int run = 0;
        for (int b = 0; b < nb; ++b) { int v = bsum[b]; bsum[b] = run; run += v; }
        off[n] = E;
    }
}

__global__ void k_scan3(const int* __restrict__ deg, int n, const int* __restrict__ bbase,
                        int* __restrict__ off, float* __restrict__ dinv) {
    __shared__ int red[256];
    int base = blockIdx.x * 1024;
    int tid = threadIdx.x;
    int d[4], t = 0;
#pragma unroll
    for (int j = 0; j < 4; ++j) {
        int i = base + tid * 4 + j;
        d[j] = (i < n) ? deg[i] : 0;
        t += d[j];
    }
    red[tid] = t;
    __syncthreads();
    for (int o = 1; o < 256; o <<= 1) {
        int v = (tid >= o) ? red[tid - o] : 0;
        __syncthreads();
        red[tid] += v;
        __syncthreads();
    }
    int run = bbase[blockIdx.x] + red[tid] - t;  // exclusive prefix
#pragma unroll
    for (int j = 0; j < 4; ++j) {
        int i = base + tid * 4 + j;
        if (i < n) {
            off[i] = run;
            dinv[i] = rsqrtf((float)(d[j] + 1));  // +1 self-loop
            run += d[j];
        }
    }
}

// ---------------- CSR fill, atomic-free: slot = off[dst] + rank ----------------
__global__ void k_csr(const int* __restrict__ edge, int E, const float* __restrict__ dinv,
                      const int* __restrict__ off, const int* __restrict__ erank,
                      int2* __restrict__ pair) {
    int e = blockIdx.x * blockDim.x + threadIdx.x;
    if (e >= E) return;
    int s = edge[e], d = edge[E + e];
    int p = off[d] + erank[e];
    pair[p] = make_int2(s, __float_as_int(dinv[s]));
}

// ---------------- fp32 -> bf16 convert ----------------
__global__ void k_cvt(const float* __restrict__ x, bf16* __restrict__ xb, int count4) {
    int i = blockIdx.x * blockDim.x + threadIdx.x;
    if (i >= count4) return;
    f32x4 v = ((const f32x4*)x)[i];
    bf16x4 o;
    o[0] = (bf16)v[0]; o[1] = (bf16)v[1]; o[2] = (bf16)v[2]; o[3] = (bf16)v[3];
    ((bf16x4*)xb)[i] = o;
}

// ---------------- W (KxNC fp32) -> Wt (NCxK bf16) ----------------
__global__ void k_wt(const float* __restrict__ W, bf16* __restrict__ Wt, int NC) {
    int nc = blockIdx.x;
    int k = threadIdx.x;
    Wt[nc * 256 + k] = (bf16)W[k * NC + nc];
}

// ---------------- agg1: ax = A @ x (256-dim). 2 nodes/wave, 16B/lane, unroll 8 ----------------
__global__ __launch_bounds__(256) void k_agg1(const bf16* __restrict__ xb,
                                              const int* __restrict__ off,
                                              const int2* __restrict__ pair,
                                              const float* __restrict__ dinv,
                                              bf16* __restrict__ ax, int n) {
    int wv = blockIdx.x * 4 + (threadIdx.x >> 6);
    int lane = threadIdx.x & 63;
    int node = wv * 2 + (lane >> 5);
    int l32 = lane & 31;
    if (node >= n) return;
    int s0 = off[node], s1 = off[node + 1];
    float dv = dinv[node];
    const bf16x8* X = (const bf16x8*)xb;
    bf16x8 xs = X[(size_t)node * 32 + l32];
    float a[8];
#pragma unroll
    for (int j = 0; j < 8; ++j) a[j] = dv * (float)xs[j];
    int e = s0;
    for (; e + 8 <= s1; e += 8) {
        int2 p[8];
#pragma unroll
        for (int q = 0; q < 8; ++q) p[q] = pair[e + q];
        bf16x8 t[8];
#pragma unroll
        for (int q = 0; q < 8; ++q) t[q] = X[(size_t)p[q].x * 32 + l32];
#pragma unroll
        for (int q = 0; q < 8; ++q) {
            float w = __int_as_float(p[q].y);
#pragma unroll
            for (int j = 0; j < 8; ++j) a[j] += w * (float)t[q][j];
        }
    }
    for (; e < s1; ++e) {
        int2 p = pair[e];
        bf16x8 t = X[(size_t)p.x * 32 + l32];
        float w = __int_as_float(p.y);
#pragma unroll
        for (int j = 0; j < 8; ++j) a[j] += w * (float)t[j];
    }
    bf16x8 o;
#pragma unroll
    for (int j = 0; j < 8; ++j) o[j] = (bf16)(a[j] * dv);
    ((bf16x8*)ax)[(size_t)node * 32 + l32] = o;
}

// ---------------- bf16 MFMA GEMM: C[n x NC] = A[n x 256] @ Bt[NC x 256]^T ----------------
template <bool BIAS_RELU>
__global__ __launch_bounds__(256) void k_gemm(const bf16* __restrict__ A,
                                              const bf16* __restrict__ Bt,
                                              const float* __restrict__ bias,
                                              bf16* __restrict__ C, int n, int NC) {
    __shared__ __align__(16) bf16 As[4 * 64 * 8];
    __shared__ __align__(16) bf16 Bs[4 * 64 * 8];
    int tid = threadIdx.x;
    int bm = blockIdx.x * 64;
    int bn = blockIdx.y * 64;
    int w = tid >> 6, lane = tid & 63;
    int wm = w >> 1, wn = w & 1;

    int r = tid >> 2;
    int cq = tid & 3;
    int lds_idx = (((r >> 4) * 64) + cq * 16 + (r & 15)) * 8;
    int arow = bm + r; if (arow > n - 1) arow = n - 1;
    int brow = bn + r;

    f32x4 acc[2][2] = {};

    for (int k0 = 0; k0 < 256; k0 += 32) {
        __syncthreads();
        uint4 av = *(const uint4*)(A + (size_t)arow * 256 + k0 + cq * 8);
        uint4 bv = *(const uint4*)(Bt + (size_t)brow * 256 + k0 + cq * 8);
        *(uint4*)(As + lds_idx) = av;
        *(uint4*)(Bs + lds_idx) = bv;
        __syncthreads();
#pragma unroll
        for (int i = 0; i < 2; ++i) {
            bf16x8 af = *(const bf16x8*)(As + ((wm * 2 + i) * 64 + lane) * 8);
#pragma unroll
            for (int j = 0; j < 2; ++j) {
                bf16x8 bfr = *(const bf16x8*)(Bs + ((wn * 2 + j) * 64 + lane) * 8);
                acc[i][j] = __builtin_amdgcn_mfma_f32_16x16x32_bf16(af, bfr, acc[i][j], 0, 0, 0);
            }
        }
    }

    int colb = lane & 15, rowq = lane >> 4;
#pragma unroll
    for (int i = 0; i < 2; ++i) {
#pragma unroll
        for (int j = 0; j < 2; ++j) {
            int col = bn + wn * 32 + j * 16 + colb;
#pragma unroll
            for (int rr = 0; rr < 4; ++rr) {
                int row = bm + wm * 32 + i * 16 + rowq * 4 + rr;
                if (row < n) {
                    float v = acc[i][j][rr];
                    if constexpr (BIAS_RELU) {
                        v += bias[col];
                        v = v > 0.0f ? v : 0.0f;
                    }
                    C[(size_t)row * NC + col] = (bf16)v;
                }
            }
        }
    }
}

// ---------------- agg2 + bias + log_softmax. 8 nodes/wave, 8 lanes/row, 16B/lane ----------------
__global__ __launch_bounds__(256) void k_agg2(const bf16* __restrict__ t,
                                              const int* __restrict__ off,
                                              const int2* __restrict__ pair,
                                              const float* __restrict__ dinv,
                                              const float* __restrict__ b2,
                                              float* __restrict__ out, int n) {
    int wv = blockIdx.x * 4 + (threadIdx.x >> 6);
    int lane = threadIdx.x & 63;
    int node = wv * 8 + (lane >> 3);
    int l8 = lane & 7;
    if (node >= n) return;
    int s0 = off[node], s1 = off[node + 1];
    float dv = dinv[node];
    const bf16x8* T = (const bf16x8*)t;  // row = 8 x bf16x8
    bf16x8 ts = T[(size_t)node * 8 + l8];
    float a[8];
#pragma unroll
    for (int j = 0; j < 8; ++j) a[j] = dv * (float)ts[j];
    int e = s0;
    for (; e + 4 <= s1; e += 4) {
        int2 p[4];
#pragma unroll
        for (int q = 0; q < 4; ++q) p[q] = pair[e + q];
        bf16x8 tv[4];
#pragma unroll
        for (int q = 0; q < 4; ++q) tv[q] = T[(size_t)p[q].x * 8 + l8];
#pragma unroll
        for (int q = 0; q < 4; ++q) {
            float w = __int_as_float(p[q].y);
#pragma unroll
            for (int j = 0; j < 8; ++j) a[j] += w * (float)tv[q][j];
        }
    }
    for (; e < s1; ++e) {
        int2 p = pair[e];
        bf16x8 tv = T[(size_t)p.x * 8 + l8];
        float w = __int_as_float(p.y);
#pragma unroll
        for (int j = 0; j < 8; ++j) a[j] += w * (float)tv[j];
    }
    const float4* B2 = (const float4*)b2;
    float4 bv0 = B2[l8 * 2], bv1 = B2[l8 * 2 + 1];
    a[0] = a[0] * dv + bv0.x; a[1] = a[1] * dv + bv0.y;
    a[2] = a[2] * dv + bv0.z; a[3] = a[3] * dv + bv0.w;
    a[4] = a[4] * dv + bv1.x; a[5] = a[5] * dv + bv1.y;
    a[6] = a[6] * dv + bv1.z; a[7] = a[7] * dv + bv1.w;
    // log_softmax over 64 cols = 8 local + xor-reduce within the 8-lane group
    float m = a[0];
#pragma unroll
    for (int j = 1; j < 8; ++j) m = fmaxf(m, a[j]);
    for (int o = 4; o > 0; o >>= 1) m = fmaxf(m, __shfl_xor(m, o));
    float s = 0.0f;
#pragma unroll
    for (int j = 0; j < 8; ++j) s += __expf(a[j] - m);
    for (int o = 4; o > 0; o >>= 1) s += __shfl_xor(s, o);
    float ls = m + __logf(s);
    f32x4 o0, o1;
    o0[0] = a[0] - ls; o0[1] = a[1] - ls; o0[2] = a[2] - ls; o0[3] = a[3] - ls;
    o1[0] = a[4] - ls; o1[1] = a[5] - ls; o1[2] = a[6] - ls; o1[3] = a[7] - ls;
    f32x4* O = (f32x4*)out;  // row = 16 x f32x4
    O[(size_t)node * 16 + l8 * 2] = o0;
    O[(size_t)node * 16 + l8 * 2 + 1] = o1;
}

extern "C" void kernel_launch(void* const* d_in, const int* in_sizes, int n_in,
                              void* d_out, int out_size, void* d_ws, size_t ws_size,
                              hipStream_t stream) {
    const float* x   = (const float*)d_in[0];
    const int*  edge = (const int*)d_in[1];
    const float* W1  = (const float*)d_in[2];
    const float* b1  = (const float*)d_in[3];
    const float* W2  = (const float*)d_in[4];
    const float* b2  = (const float*)d_in[5];
    float* out = (float*)d_out;

    int n = in_sizes[0] / 256;   // 100000
    int E = in_sizes[1] / 2;     // 3200000
    int nb = (n + 1023) / 1024;  // scan chunks

    char* ws = (char*)d_ws;
    auto alloc = [&](size_t bytes) -> char* {
        char* p = ws;
        ws += (bytes + 255) & ~(size_t)255;
        return p;
    };
    int*   deg   = (int*)alloc((size_t)n * 4);
    float* dinv  = (float*)alloc((size_t)n * 4);
    int*   off   = (int*)alloc((size_t)(n + 1) * 4);
    int*   erank = (int*)alloc((size_t)E * 4);
    int*   bsum  = (int*)alloc((size_t)nb * 4);
    int2*  pair  = (int2*)alloc((size_t)E * 8);
    bf16*  xb    = (bf16*)alloc((size_t)n * 256 * 2);
    bf16*  ax    = (bf16*)alloc((size_t)n * 256 * 2);
    bf16*  tb    = (bf16*)alloc((size_t)n * 64 * 2);
    bf16*  W1t   = (bf16*)alloc(256 * 256 * 2);
    bf16*  W2t   = (bf16*)alloc(64 * 256 * 2);
    bf16*  h1    = xb;  // xb dead after agg1; reuse for h1

    hipMemsetAsync(deg, 0, (size_t)n * 4, stream);
    k_deg<<<(E + 255) / 256, 256, 0, stream>>>(edge, E, deg, erank);
    k_scan1<<<nb, 256, 0, stream>>>(deg, n, bsum);
    k_scan2<<<1, 64, 0, stream>>>(bsum, nb, E, off, n);
    k_scan3<<<nb, 256, 0, stream>>>(deg, n, bsum, off, dinv);
    k_csr<<<(E + 255) / 256, 256, 0, stream>>>(edge, E, dinv, off, erank, pair);
    k_cvt<<<(n * 64 + 255) / 256, 256, 0, stream>>>(x, xb, n * 64);
    k_wt<<<256, 256, 0, stream>>>(W1, W1t, 256);
    k_wt<<<64, 256, 0, stream>>>(W2, W2t, 64);

    k_agg1<<<(n + 7) / 8, 256, 0, stream>>>(xb, off, pair, dinv, ax, n);

    dim3 g1((n + 63) / 64, 4);
    k_gemm<true><<<g1, 256, 0, stream>>>(ax, W1t, b1, h1, n, 256);
    dim3 g2((n + 63) / 64, 1);
    k_gemm<false><<<g2, 256, 0, stream>>>(h1, W2t, nullptr, tb, n, 64);

    k_agg2<<<(n + 31) / 32, 256, 0, stream>>>(tb, off, pair, dinv, b2, out, n);
}

// Round 4
// 655.881 us; speedup vs baseline: 2.1788x; 1.1516x over previous
//
#include <hip/hip_runtime.h>
#include <hip/hip_bf16.h>

// BasicGCN: out = log_softmax( A @ (relu(A @ x @ W1 + b1) @ W2) + b2 )
// A = sym-normalized adjacency with self-loops.
// Layer1 computed as (A@x)@W1 ; layer2 as A@(h1@W2) (64-dim aggregation).
// R4: x gather table quantized to per-row-scaled int8 (halves agg1's L2-miss
// bytes; agg1 is at the random-gather fabric ceiling ~3.8 TB/s). agg2/GEMMs
// unchanged. pair.y stays dinv[src]; agg1 gathers scale[src] per edge.

typedef __bf16 bf16;
typedef bf16 bf16x2 __attribute__((ext_vector_type(2)));
typedef bf16 bf16x4 __attribute__((ext_vector_type(4)));
typedef bf16 bf16x8 __attribute__((ext_vector_type(8)));
typedef float f32x4 __attribute__((ext_vector_type(4)));
typedef signed char s8;
typedef signed char s8x8 __attribute__((ext_vector_type(8)));

// ---------------- degree histogram + per-edge rank ----------------
__global__ void k_deg(const int* __restrict__ edge, int E, int* __restrict__ deg,
                      int* __restrict__ erank) {
    int e = blockIdx.x * blockDim.x + threadIdx.x;
    if (e < E) erank[e] = atomicAdd(&deg[edge[E + e]], 1);
}

// ---------------- parallel scan (3 tiny kernels over 1024-node chunks) ----------------
__global__ void k_scan1(const int* __restrict__ deg, int n, int* __restrict__ bsum) {
    __shared__ int red[256];
    int base = blockIdx.x * 1024;
    int tid = threadIdx.x;
    int s = 0;
#pragma unroll
    for (int j = 0; j < 4; ++j) {
        int i = base + j * 256 + tid;
        if (i < n) s += deg[i];
    }
    red[tid] = s;
    __syncthreads();
    for (int o = 128; o > 0; o >>= 1) {
        if (tid < o) red[tid] += red[tid + o];
        __syncthreads();
    }
    if (tid == 0) bsum[blockIdx.x] = red[0];
}

__global__ void k_scan2(int* __restrict__ bsum, int nb, int E, int* __restrict__ off, int n) {
    if (threadIdx.x == 0) {
        int run = 0;
        for (int b = 0; b < nb; ++b) { int v = bsum[b]; bsum[b] = run; run += v; }
        off[n] = E;
    }
}

__global__ void k_scan3(const int* __restrict__ deg, int n, const int* __restrict__ bbase,
                        int* __restrict__ off, float* __restrict__ dinv) {
    __shared__ int red[256];
    int base = blockIdx.x * 1024;
    int tid = threadIdx.x;
    int d[4], t = 0;
#pragma unroll
    for (int j = 0; j < 4; ++j) {
        int i = base + tid * 4 + j;
        d[j] = (i < n) ? deg[i] : 0;
        t += d[j];
    }
    red[tid] = t;
    __syncthreads();
    for (int o = 1; o < 256; o <<= 1) {
        int v = (tid >= o) ? red[tid - o] : 0;
        __syncthreads();
        red[tid] += v;
        __syncthreads();
    }
    int run = bbase[blockIdx.x] + red[tid] - t;  // exclusive prefix
#pragma unroll
    for (int j = 0; j < 4; ++j) {
        int i = base + tid * 4 + j;
        if (i < n) {
            off[i] = run;
            dinv[i] = rsqrtf((float)(d[j] + 1));  // +1 self-loop
            run += d[j];
        }
    }
}

// ---------------- CSR fill, atomic-free: slot = off[dst] + rank ----------------
__global__ void k_csr(const int* __restrict__ edge, int E, const float* __restrict__ dinv,
                      const int* __restrict__ off, const int* __restrict__ erank,
                      int2* __restrict__ pair) {
    int e = blockIdx.x * blockDim.x + threadIdx.x;
    if (e >= E) return;
    int s = edge[e], d = edge[E + e];
    int p = off[d] + erank[e];
    pair[p] = make_int2(s, __float_as_int(dinv[s]));
}

// ---------------- x -> per-row-scaled int8 (one wave per row) ----------------
__global__ __launch_bounds__(256) void k_quant(const float* __restrict__ x,
                                               s8* __restrict__ xq,
                                               float* __restrict__ scale, int n) {
    int row = blockIdx.x * 4 + (threadIdx.x >> 6);
    int lane = threadIdx.x & 63;
    if (row >= n) return;
    f32x4 v = ((const f32x4*)x)[(size_t)row * 64 + lane];
    float m = fmaxf(fmaxf(fabsf(v[0]), fabsf(v[1])), fmaxf(fabsf(v[2]), fabsf(v[3])));
    for (int o = 32; o > 0; o >>= 1) m = fmaxf(m, __shfl_xor(m, o));
    m = fmaxf(m, 1e-20f);
    float inv = 127.0f / m;
    int b0 = __float2int_rn(v[0] * inv) & 255;
    int b1 = __float2int_rn(v[1] * inv) & 255;
    int b2 = __float2int_rn(v[2] * inv) & 255;
    int b3 = __float2int_rn(v[3] * inv) & 255;
    ((int*)xq)[(size_t)row * 64 + lane] = b0 | (b1 << 8) | (b2 << 16) | (b3 << 24);
    if (lane == 0) scale[row] = m / 127.0f;
}

// ---------------- W (KxNC fp32) -> Wt (NCxK bf16) ----------------
__global__ void k_wt(const float* __restrict__ W, bf16* __restrict__ Wt, int NC) {
    int nc = blockIdx.x;
    int k = threadIdx.x;
    Wt[nc * 256 + k] = (bf16)W[k * NC + nc];
}

// ---------------- agg1: ax = A @ x (int8 table). 2 nodes/wave, 8B/lane, unroll 8 ----------------
__global__ __launch_bounds__(256) void k_agg1(const s8* __restrict__ xq,
                                              const float* __restrict__ scale,
                                              const int* __restrict__ off,
                                              const int2* __restrict__ pair,
                                              const float* __restrict__ dinv,
                                              bf16* __restrict__ ax, int n) {
    int wv = blockIdx.x * 4 + (threadIdx.x >> 6);
    int lane = threadIdx.x & 63;
    int node = wv * 2 + (lane >> 5);
    int l32 = lane & 31;
    if (node >= n) return;
    int s0 = off[node], s1 = off[node + 1];
    float dv = dinv[node];
    const s8x8* X = (const s8x8*)xq;
    s8x8 xs = X[(size_t)node * 32 + l32];
    float ws = dv * scale[node];
    float a[8];
#pragma unroll
    for (int j = 0; j < 8; ++j) a[j] = ws * (float)xs[j];
    int e = s0;
    for (; e + 8 <= s1; e += 8) {
        int2 p[8];
#pragma unroll
        for (int q = 0; q < 8; ++q) p[q] = pair[e + q];
        float sc[8];
#pragma unroll
        for (int q = 0; q < 8; ++q) sc[q] = scale[p[q].x];
        s8x8 t[8];
#pragma unroll
        for (int q = 0; q < 8; ++q) t[q] = X[(size_t)p[q].x * 32 + l32];
#pragma unroll
        for (int q = 0; q < 8; ++q) {
            float w = __int_as_float(p[q].y) * sc[q];
#pragma unroll
            for (int j = 0; j < 8; ++j) a[j] += w * (float)t[q][j];
        }
    }
    for (; e < s1; ++e) {
        int2 p = pair[e];
        float w = __int_as_float(p.y) * scale[p.x];
        s8x8 t = X[(size_t)p.x * 32 + l32];
#pragma unroll
        for (int j = 0; j < 8; ++j) a[j] += w * (float)t[j];
    }
    bf16x8 o;
#pragma unroll
    for (int j = 0; j < 8; ++j) o[j] = (bf16)(a[j] * dv);
    // ax row = 256 bf16 = 32 x bf16x8; this wave-half covers elems [l32*8, l32*8+8)
    ((bf16x8*)ax)[(size_t)node * 32 + l32] = o;
}

// ---------------- bf16 MFMA GEMM: C[n x NC] = A[n x 256] @ Bt[NC x 256]^T ----------------
template <bool BIAS_RELU>
__global__ __launch_bounds__(256) void k_gemm(const bf16* __restrict__ A,
                                              const bf16* __restrict__ Bt,
                                              const float* __restrict__ bias,
                                              bf16* __restrict__ C, int n, int NC) {
    __shared__ __align__(16) bf16 As[4 * 64 * 8];
    __shared__ __align__(16) bf16 Bs[4 * 64 * 8];
    int tid = threadIdx.x;
    int bm = blockIdx.x * 64;
    int bn = blockIdx.y * 64;
    int w = tid >> 6, lane = tid & 63;
    int wm = w >> 1, wn = w & 1;

    int r = tid >> 2;
    int cq = tid & 3;
    int lds_idx = (((r >> 4) * 64) + cq * 16 + (r & 15)) * 8;
    int arow = bm + r; if (arow > n - 1) arow = n - 1;
    int brow = bn + r;

    f32x4 acc[2][2] = {};

    for (int k0 = 0; k0 < 256; k0 += 32) {
        __syncthreads();
        uint4 av = *(const uint4*)(A + (size_t)arow * 256 + k0 + cq * 8);
        uint4 bv = *(const uint4*)(Bt + (size_t)brow * 256 + k0 + cq * 8);
        *(uint4*)(As + lds_idx) = av;
        *(uint4*)(Bs + lds_idx) = bv;
        __syncthreads();
#pragma unroll
        for (int i = 0; i < 2; ++i) {
            bf16x8 af = *(const bf16x8*)(As + ((wm * 2 + i) * 64 + lane) * 8);
#pragma unroll
            for (int j = 0; j < 2; ++j) {
                bf16x8 bfr = *(const bf16x8*)(Bs + ((wn * 2 + j) * 64 + lane) * 8);
                acc[i][j] = __builtin_amdgcn_mfma_f32_16x16x32_bf16(af, bfr, acc[i][j], 0, 0, 0);
            }
        }
    }

    int colb = lane & 15, rowq = lane >> 4;
#pragma unroll
    for (int i = 0; i < 2; ++i) {
#pragma unroll
        for (int j = 0; j < 2; ++j) {
            int col = bn + wn * 32 + j * 16 + colb;
#pragma unroll
            for (int rr = 0; rr < 4; ++rr) {
                int row = bm + wm * 32 + i * 16 + rowq * 4 + rr;
                if (row < n) {
                    float v = acc[i][j][rr];
                    if constexpr (BIAS_RELU) {
                        v += bias[col];
                        v = v > 0.0f ? v : 0.0f;
                    }
                    C[(size_t)row * NC + col] = (bf16)v;
                }
            }
        }
    }
}

// ---------------- agg2 + bias + log_softmax. 8 nodes/wave, 8 lanes/row, 16B/lane ----------------
__global__ __launch_bounds__(256) void k_agg2(const bf16* __restrict__ t,
                                              const int* __restrict__ off,
                                              const int2* __restrict__ pair,
                                              const float* __restrict__ dinv,
                                              const float* __restrict__ b2,
                                              float* __restrict__ out, int n) {
    int wv = blockIdx.x * 4 + (threadIdx.x >> 6);
    int lane = threadIdx.x & 63;
    int node = wv * 8 + (lane >> 3);
    int l8 = lane & 7;
    if (node >= n) return;
    int s0 = off[node], s1 = off[node + 1];
    float dv = dinv[node];
    const bf16x8* T = (const bf16x8*)t;  // row = 8 x bf16x8
    bf16x8 ts = T[(size_t)node * 8 + l8];
    float a[8];
#pragma unroll
    for (int j = 0; j < 8; ++j) a[j] = dv * (float)ts[j];
    int e = s0;
    for (; e + 4 <= s1; e += 4) {
        int2 p[4];
#pragma unroll
        for (int q = 0; q < 4; ++q) p[q] = pair[e + q];
        bf16x8 tv[4];
#pragma unroll
        for (int q = 0; q < 4; ++q) tv[q] = T[(size_t)p[q].x * 8 + l8];
#pragma unroll
        for (int q = 0; q < 4; ++q) {
            float w = __int_as_float(p[q].y);
#pragma unroll
            for (int j = 0; j < 8; ++j) a[j] += w * (float)tv[q][j];
        }
    }
    for (; e < s1; ++e) {
        int2 p = pair[e];
        bf16x8 tv = T[(size_t)p.x * 8 + l8];
        float w = __int_as_float(p.y);
#pragma unroll
        for (int j = 0; j < 8; ++j) a[j] += w * (float)tv[j];
    }
    const float4* B2 = (const float4*)b2;
    float4 bv0 = B2[l8 * 2], bv1 = B2[l8 * 2 + 1];
    a[0] = a[0] * dv + bv0.x; a[1] = a[1] * dv + bv0.y;
    a[2] = a[2] * dv + bv0.z; a[3] = a[3] * dv + bv0.w;
    a[4] = a[4] * dv + bv1.x; a[5] = a[5] * dv + bv1.y;
    a[6] = a[6] * dv + bv1.z; a[7] = a[7] * dv + bv1.w;
    float m = a[0];
#pragma unroll
    for (int j = 1; j < 8; ++j) m = fmaxf(m, a[j]);
    for (int o = 4; o > 0; o >>= 1) m = fmaxf(m, __shfl_xor(m, o));
    float s = 0.0f;
#pragma unroll
    for (int j = 0; j < 8; ++j) s += __expf(a[j] - m);
    for (int o = 4; o > 0; o >>= 1) s += __shfl_xor(s, o);
    float ls = m + __logf(s);
    f32x4 o0, o1;
    o0[0] = a[0] - ls; o0[1] = a[1] - ls; o0[2] = a[2] - ls; o0[3] = a[3] - ls;
    o1[0] = a[4] - ls; o1[1] = a[5] - ls; o1[2] = a[6] - ls; o1[3] = a[7] - ls;
    f32x4* O = (f32x4*)out;  // row = 16 x f32x4
    O[(size_t)node * 16 + l8 * 2] = o0;
    O[(size_t)node * 16 + l8 * 2 + 1] = o1;
}

extern "C" void kernel_launch(void* const* d_in, const int* in_sizes, int n_in,
                              void* d_out, int out_size, void* d_ws, size_t ws_size,
                              hipStream_t stream) {
    const float* x   = (const float*)d_in[0];
    const int*  edge = (const int*)d_in[1];
    const float* W1  = (const float*)d_in[2];
    const float* b1  = (const float*)d_in[3];
    const float* W2  = (const float*)d_in[4];
    const float* b2  = (const float*)d_in[5];
    float* out = (float*)d_out;

    int n = in_sizes[0] / 256;   // 100000
    int E = in_sizes[1] / 2;     // 3200000
    int nb = (n + 1023) / 1024;  // scan chunks

    char* ws = (char*)d_ws;
    auto alloc = [&](size_t bytes) -> char* {
        char* p = ws;
        ws += (bytes + 255) & ~(size_t)255;
        return p;
    };
    int*   deg   = (int*)alloc((size_t)n * 4);
    float* dinv  = (float*)alloc((size_t)n * 4);
    int*   off   = (int*)alloc((size_t)(n + 1) * 4);
    int*   erank = (int*)alloc((size_t)E * 4);
    int*   bsum  = (int*)alloc((size_t)nb * 4);
    int2*  pair  = (int2*)alloc((size_t)E * 8);
    s8*    xq    = (s8*)alloc((size_t)n * 256);
    float* scale = (float*)alloc((size_t)n * 4);
    bf16*  ax    = (bf16*)alloc((size_t)n * 256 * 2);
    bf16*  h1    = (bf16*)alloc((size_t)n * 256 * 2);
    bf16*  tb    = (bf16*)alloc((size_t)n * 64 * 2);
    bf16*  W1t   = (bf16*)alloc(256 * 256 * 2);
    bf16*  W2t   = (bf16*)alloc(64 * 256 * 2);

    hipMemsetAsync(deg, 0, (size_t)n * 4, stream);
    k_deg<<<(E + 255) / 256, 256, 0, stream>>>(edge, E, deg, erank);
    k_scan1<<<nb, 256, 0, stream>>>(deg, n, bsum);
    k_scan2<<<1, 64, 0, stream>>>(bsum, nb, E, off, n);
    k_scan3<<<nb, 256, 0, stream>>>(deg, n, bsum, off, dinv);
    k_csr<<<(E + 255) / 256, 256, 0, stream>>>(edge, E, dinv, off, erank, pair);
    k_quant<<<(n + 3) / 4, 256, 0, stream>>>(x, xq, scale, n);
    k_wt<<<256, 256, 0, stream>>>(W1, W1t, 256);
    k_wt<<<64, 256, 0, stream>>>(W2, W2t, 64);

    k_agg1<<<(n + 7) / 8, 256, 0, stream>>>(xq, scale, off, pair, dinv, ax, n);

    dim3 g1((n + 63) / 64, 4);
    k_gemm<true><<<g1, 256, 0, stream>>>(ax, W1t, b1, h1, n, 256);
    dim3 g2((n + 63) / 64, 1);
    k_gemm<false><<<g2, 256, 0, stream>>>(h1, W2t, nullptr, tb, n, 64);

    k_agg2<<<(n + 31) / 32, 256, 0, stream>>>(tb, off, pair, dinv, b2, out, n);
}

// Round 5
// 648.443 us; speedup vs baseline: 2.2038x; 1.0115x over previous
//
#include <hip/hip_runtime.h>
#include <hip/hip_bf16.h>

// BasicGCN: out = log_softmax( A @ (relu(A @ x @ W1 + b1) @ W2) + b2 )
// A = sym-normalized adjacency with self-loops.
// Layer1 computed as (A@x)@W1 ; layer2 as A@(h1@W2) (64-dim aggregation).
// R5: (1) degree histogram padded to one bin per 128B L2 line (atomic line
// contention was 1024 ops/line -> 32); (2) layer-2 gather table quantized to
// per-row int8 like agg1's (halves agg2 random-gather bytes).

typedef __bf16 bf16;
typedef bf16 bf16x4 __attribute__((ext_vector_type(4)));
typedef bf16 bf16x8 __attribute__((ext_vector_type(8)));
typedef float f32x4 __attribute__((ext_vector_type(4)));
typedef signed char s8;
typedef signed char s8x8 __attribute__((ext_vector_type(8)));

#define DEGS 32  // histogram bin stride in ints (one bin per 128B line)

// ---------------- degree histogram (padded bins) + per-edge rank ----------------
__global__ void k_deg(const int* __restrict__ edge, int E, int* __restrict__ degp,
                      int* __restrict__ erank) {
    int e = blockIdx.x * blockDim.x + threadIdx.x;
    if (e < E) erank[e] = atomicAdd(&degp[(size_t)edge[E + e] * DEGS], 1);
}

// ---------------- parallel scan (3 tiny kernels over 1024-node chunks) ----------------
__global__ void k_scan1(const int* __restrict__ degp, int n, int* __restrict__ bsum) {
    __shared__ int red[256];
    int base = blockIdx.x * 1024;
    int tid = threadIdx.x;
    int s = 0;
#pragma unroll
    for (int j = 0; j < 4; ++j) {
        int i = base + j * 256 + tid;
        if (i < n) s += degp[(size_t)i * DEGS];
    }
    red[tid] = s;
    __syncthreads();
    for (int o = 128; o > 0; o >>= 1) {
        if (tid < o) red[tid] += red[tid + o];
        __syncthreads();
    }
    if (tid == 0) bsum[blockIdx.x] = red[0];
}

__global__ void k_scan2(int* __restrict__ bsum, int nb, int E, int* __restrict__ off, int n) {
    if (threadIdx.x == 0) {
        int run = 0;
        for (int b = 0; b < nb; ++b) { int v = bsum[b]; bsum[b] = run; run += v; }
        off[n] = E;
    }
}

__global__ void k_scan3(const int* __restrict__ degp, int n, const int* __restrict__ bbase,
                        int* __restrict__ off, float* __restrict__ dinv) {
    __shared__ int red[256];
    int base = blockIdx.x * 1024;
    int tid = threadIdx.x;
    int d[4], t = 0;
#pragma unroll
    for (int j = 0; j < 4; ++j) {
        int i = base + tid * 4 + j;
        d[j] = (i < n) ? degp[(size_t)i * DEGS] : 0;
        t += d[j];
    }
    red[tid] = t;
    __syncthreads();
    for (int o = 1; o < 256; o <<= 1) {
        int v = (tid >= o) ? red[tid - o] : 0;
        __syncthreads();
        red[tid] += v;
        __syncthreads();
    }
    int run = bbase[blockIdx.x] + red[tid] - t;  // exclusive prefix
#pragma unroll
    for (int j = 0; j < 4; ++j) {
        int i = base + tid * 4 + j;
        if (i < n) {
            off[i] = run;
            dinv[i] = rsqrtf((float)(d[j] + 1));  // +1 self-loop
            run += d[j];
        }
    }
}

// ---------------- CSR fill, atomic-free: slot = off[dst] + rank ----------------
__global__ void k_csr(const int* __restrict__ edge, int E, const float* __restrict__ dinv,
                      const int* __restrict__ off, const int* __restrict__ erank,
                      int2* __restrict__ pair) {
    int e = blockIdx.x * blockDim.x + threadIdx.x;
    if (e >= E) return;
    int s = edge[e], d = edge[E + e];
    int p = off[d] + erank[e];
    pair[p] = make_int2(s, __float_as_int(dinv[s]));
}

// ---------------- x -> per-row-scaled int8 (one wave per row) ----------------
__global__ __launch_bounds__(256) void k_quant(const float* __restrict__ x,
                                               s8* __restrict__ xq,
                                               float* __restrict__ scale, int n) {
    int row = blockIdx.x * 4 + (threadIdx.x >> 6);
    int lane = threadIdx.x & 63;
    if (row >= n) return;
    f32x4 v = ((const f32x4*)x)[(size_t)row * 64 + lane];
    float m = fmaxf(fmaxf(fabsf(v[0]), fabsf(v[1])), fmaxf(fabsf(v[2]), fabsf(v[3])));
    for (int o = 32; o > 0; o >>= 1) m = fmaxf(m, __shfl_xor(m, o));
    m = fmaxf(m, 1e-20f);
    float inv = 127.0f / m;
    int b0 = __float2int_rn(v[0] * inv) & 255;
    int b1 = __float2int_rn(v[1] * inv) & 255;
    int b2 = __float2int_rn(v[2] * inv) & 255;
    int b3 = __float2int_rn(v[3] * inv) & 255;
    ((int*)xq)[(size_t)row * 64 + lane] = b0 | (b1 << 8) | (b2 << 16) | (b3 << 24);
    if (lane == 0) scale[row] = m / 127.0f;
}

// ---------------- tb (n x 64 bf16) -> per-row int8 + scale. 8 lanes/row ----------------
__global__ __launch_bounds__(256) void k_quant2(const bf16* __restrict__ tb,
                                                s8* __restrict__ tq,
                                                float* __restrict__ tscale, int n) {
    int t = blockIdx.x * 256 + threadIdx.x;
    int row = t >> 3;
    int l8 = t & 7;
    if (row >= n) return;
    bf16x8 v = ((const bf16x8*)tb)[(size_t)row * 8 + l8];
    float f[8], m = 0.0f;
#pragma unroll
    for (int j = 0; j < 8; ++j) { f[j] = (float)v[j]; m = fmaxf(m, fabsf(f[j])); }
    for (int o = 4; o > 0; o >>= 1) m = fmaxf(m, __shfl_xor(m, o));
    m = fmaxf(m, 1e-20f);
    float inv = 127.0f / m;
    int lo = 0, hi = 0;
#pragma unroll
    for (int j = 0; j < 4; ++j) lo |= (__float2int_rn(f[j] * inv) & 255) << (8 * j);
#pragma unroll
    for (int j = 0; j < 4; ++j) hi |= (__float2int_rn(f[4 + j] * inv) & 255) << (8 * j);
    ((int2*)tq)[(size_t)row * 8 + l8] = make_int2(lo, hi);
    if (l8 == 0) tscale[row] = m / 127.0f;
}

// ---------------- W (KxNC fp32) -> Wt (NCxK bf16) ----------------
__global__ void k_wt(const float* __restrict__ W, bf16* __restrict__ Wt, int NC) {
    int nc = blockIdx.x;
    int k = threadIdx.x;
    Wt[nc * 256 + k] = (bf16)W[k * NC + nc];
}

// ---------------- agg1: ax = A @ x (int8 table). 2 nodes/wave, 8B/lane, unroll 8 ----------------
__global__ __launch_bounds__(256) void k_agg1(const s8* __restrict__ xq,
                                              const float* __restrict__ scale,
                                              const int* __restrict__ off,
                                              const int2* __restrict__ pair,
                                              const float* __restrict__ dinv,
                                              bf16* __restrict__ ax, int n) {
    int wv = blockIdx.x * 4 + (threadIdx.x >> 6);
    int lane = threadIdx.x & 63;
    int node = wv * 2 + (lane >> 5);
    int l32 = lane & 31;
    if (node >= n) return;
    int s0 = off[node], s1 = off[node + 1];
    float dv = dinv[node];
    const s8x8* X = (const s8x8*)xq;
    s8x8 xs = X[(size_t)node * 32 + l32];
    float ws = dv * scale[node];
    float a[8];
#pragma unroll
    for (int j = 0; j < 8; ++j) a[j] = ws * (float)xs[j];
    int e = s0;
    for (; e + 8 <= s1; e += 8) {
        int2 p[8];
#pragma unroll
        for (int q = 0; q < 8; ++q) p[q] = pair[e + q];
        float sc[8];
#pragma unroll
        for (int q = 0; q < 8; ++q) sc[q] = scale[p[q].x];
        s8x8 t[8];
#pragma unroll
        for (int q = 0; q < 8; ++q) t[q] = X[(size_t)p[q].x * 32 + l32];
#pragma unroll
        for (int q = 0; q < 8; ++q) {
            float w = __int_as_float(p[q].y) * sc[q];
#pragma unroll
            for (int j = 0; j < 8; ++j) a[j] += w * (float)t[q][j];
        }
    }
    for (; e < s1; ++e) {
        int2 p = pair[e];
        float w = __int_as_float(p.y) * scale[p.x];
        s8x8 t = X[(size_t)p.x * 32 + l32];
#pragma unroll
        for (int j = 0; j < 8; ++j) a[j] += w * (float)t[j];
    }
    bf16x8 o;
#pragma unroll
    for (int j = 0; j < 8; ++j) o[j] = (bf16)(a[j] * dv);
    ((bf16x8*)ax)[(size_t)node * 32 + l32] = o;
}

// ---------------- bf16 MFMA GEMM: C[n x NC] = A[n x 256] @ Bt[NC x 256]^T ----------------
template <bool BIAS_RELU>
__global__ __launch_bounds__(256) void k_gemm(const bf16* __restrict__ A,
                                              const bf16* __restrict__ Bt,
                                              const float* __restrict__ bias,
                                              bf16* __restrict__ C, int n, int NC) {
    __shared__ __align__(16) bf16 As[4 * 64 * 8];
    __shared__ __align__(16) bf16 Bs[4 * 64 * 8];
    int tid = threadIdx.x;
    int bm = blockIdx.x * 64;
    int bn = blockIdx.y * 64;
    int w = tid >> 6, lane = tid & 63;
    int wm = w >> 1, wn = w & 1;

    int r = tid >> 2;
    int cq = tid & 3;
    int lds_idx = (((r >> 4) * 64) + cq * 16 + (r & 15)) * 8;
    int arow = bm + r; if (arow > n - 1) arow = n - 1;
    int brow = bn + r;

    f32x4 acc[2][2] = {};

    for (int k0 = 0; k0 < 256; k0 += 32) {
        __syncthreads();
        uint4 av = *(const uint4*)(A + (size_t)arow * 256 + k0 + cq * 8);
        uint4 bv = *(const uint4*)(Bt + (size_t)brow * 256 + k0 + cq * 8);
        *(uint4*)(As + lds_idx) = av;
        *(uint4*)(Bs + lds_idx) = bv;
        __syncthreads();
#pragma unroll
        for (int i = 0; i < 2; ++i) {
            bf16x8 af = *(const bf16x8*)(As + ((wm * 2 + i) * 64 + lane) * 8);
#pragma unroll
            for (int j = 0; j < 2; ++j) {
                bf16x8 bfr = *(const bf16x8*)(Bs + ((wn * 2 + j) * 64 + lane) * 8);
                acc[i][j] = __builtin_amdgcn_mfma_f32_16x16x32_bf16(af, bfr, acc[i][j], 0, 0, 0);
            }
        }
    }

    int colb = lane & 15, rowq = lane >> 4;
#pragma unroll
    for (int i = 0; i < 2; ++i) {
#pragma unroll
        for (int j = 0; j < 2; ++j) {
            int col = bn + wn * 32 + j * 16 + colb;
#pragma unroll
            for (int rr = 0; rr < 4; ++rr) {
                int row = bm + wm * 32 + i * 16 + rowq * 4 + rr;
                if (row < n) {
                    float v = acc[i][j][rr];
                    if constexpr (BIAS_RELU) {
                        v += bias[col];
                        v = v > 0.0f ? v : 0.0f;
                    }
                    C[(size_t)row * NC + col] = (bf16)v;
                }
            }
        }
    }
}

// ---------------- agg2 (int8 table) + bias + log_softmax. 8 nodes/wave, 8 lanes/row ----------------
__global__ __launch_bounds__(256) void k_agg2(const s8* __restrict__ tq,
                                              const float* __restrict__ tscale,
                                              const int* __restrict__ off,
                                              const int2* __restrict__ pair,
                                              const float* __restrict__ dinv,
                                              const float* __restrict__ b2,
                                              float* __restrict__ out, int n) {
    int wv = blockIdx.x * 4 + (threadIdx.x >> 6);
    int lane = threadIdx.x & 63;
    int node = wv * 8 + (lane >> 3);
    int l8 = lane & 7;
    if (node >= n) return;
    int s0 = off[node], s1 = off[node + 1];
    float dv = dinv[node];
    const s8x8* T = (const s8x8*)tq;  // row = 8 x s8x8 (64B)
    s8x8 ts = T[(size_t)node * 8 + l8];
    float ws = dv * tscale[node];
    float a[8];
#pragma unroll
    for (int j = 0; j < 8; ++j) a[j] = ws * (float)ts[j];
    int e = s0;
    for (; e + 4 <= s1; e += 4) {
        int2 p[4];
#pragma unroll
        for (int q = 0; q < 4; ++q) p[q] = pair[e + q];
        float sc[4];
#pragma unroll
        for (int q = 0; q < 4; ++q) sc[q] = tscale[p[q].x];
        s8x8 tv[4];
#pragma unroll
        for (int q = 0; q < 4; ++q) tv[q] = T[(size_t)p[q].x * 8 + l8];
#pragma unroll
        for (int q = 0; q < 4; ++q) {
            float w = __int_as_float(p[q].y) * sc[q];
#pragma unroll
            for (int j = 0; j < 8; ++j) a[j] += w * (float)tv[q][j];
        }
    }
    for (; e < s1; ++e) {
        int2 p = pair[e];
        float w = __int_as_float(p.y) * tscale[p.x];
        s8x8 tv = T[(size_t)p.x * 8 + l8];
#pragma unroll
        for (int j = 0; j < 8; ++j) a[j] += w * (float)tv[j];
    }
    const float4* B2 = (const float4*)b2;
    float4 bv0 = B2[l8 * 2], bv1 = B2[l8 * 2 + 1];
    a[0] = a[0] * dv + bv0.x; a[1] = a[1] * dv + bv0.y;
    a[2] = a[2] * dv + bv0.z; a[3] = a[3] * dv + bv0.w;
    a[4] = a[4] * dv + bv1.x; a[5] = a[5] * dv + bv1.y;
    a[6] = a[6] * dv + bv1.z; a[7] = a[7] * dv + bv1.w;
    float m = a[0];
#pragma unroll
    for (int j = 1; j < 8; ++j) m = fmaxf(m, a[j]);
    for (int o = 4; o > 0; o >>= 1) m = fmaxf(m, __shfl_xor(m, o));
    float s = 0.0f;
#pragma unroll
    for (int j = 0; j < 8; ++j) s += __expf(a[j] - m);
    for (int o = 4; o > 0; o >>= 1) s += __shfl_xor(s, o);
    float ls = m + __logf(s);
    f32x4 o0, o1;
    o0[0] = a[0] - ls; o0[1] = a[1] - ls; o0[2] = a[2] - ls; o0[3] = a[3] - ls;
    o1[0] = a[4] - ls; o1[1] = a[5] - ls; o1[2] = a[6] - ls; o1[3] = a[7] - ls;
    f32x4* O = (f32x4*)out;  // row = 16 x f32x4
    O[(size_t)node * 16 + l8 * 2] = o0;
    O[(size_t)node * 16 + l8 * 2 + 1] = o1;
}

extern "C" void kernel_launch(void* const* d_in, const int* in_sizes, int n_in,
                              void* d_out, int out_size, void* d_ws, size_t ws_size,
                              hipStream_t stream) {
    const float* x   = (const float*)d_in[0];
    const int*  edge = (const int*)d_in[1];
    const float* W1  = (const float*)d_in[2];
    const float* b1  = (const float*)d_in[3];
    const float* W2  = (const float*)d_in[4];
    const float* b2  = (const float*)d_in[5];
    float* out = (float*)d_out;

    int n = in_sizes[0] / 256;   // 100000
    int E = in_sizes[1] / 2;     // 3200000
    int nb = (n + 1023) / 1024;  // scan chunks

    char* ws = (char*)d_ws;
    auto alloc = [&](size_t bytes) -> char* {
        char* p = ws;
        ws += (bytes + 255) & ~(size_t)255;
        return p;
    };
    int*   degp   = (int*)alloc((size_t)n * DEGS * 4);
    float* dinv   = (float*)alloc((size_t)n * 4);
    int*   off    = (int*)alloc((size_t)(n + 1) * 4);
    int*   erank  = (int*)alloc((size_t)E * 4);
    int*   bsum   = (int*)alloc((size_t)nb * 4);
    int2*  pair   = (int2*)alloc((size_t)E * 8);
    s8*    xq     = (s8*)alloc((size_t)n * 256);
    float* scale  = (float*)alloc((size_t)n * 4);
    bf16*  ax     = (bf16*)alloc((size_t)n * 256 * 2);
    bf16*  h1     = (bf16*)alloc((size_t)n * 256 * 2);
    bf16*  tb     = (bf16*)alloc((size_t)n * 64 * 2);
    s8*    tq     = (s8*)alloc((size_t)n * 64);
    float* tscale = (float*)alloc((size_t)n * 4);
    bf16*  W1t    = (bf16*)alloc(256 * 256 * 2);
    bf16*  W2t    = (bf16*)alloc(64 * 256 * 2);

    hipMemsetAsync(degp, 0, (size_t)n * DEGS * 4, stream);
    k_deg<<<(E + 255) / 256, 256, 0, stream>>>(edge, E, degp, erank);
    k_scan1<<<nb, 256, 0, stream>>>(degp, n, bsum);
    k_scan2<<<1, 64, 0, stream>>>(bsum, nb, E, off, n);
    k_scan3<<<nb, 256, 0, stream>>>(degp, n, bsum, off, dinv);
    k_csr<<<(E + 255) / 256, 256, 0, stream>>>(edge, E, dinv, off, erank, pair);
    k_quant<<<(n + 3) / 4, 256, 0, stream>>>(x, xq, scale, n);
    k_wt<<<256, 256, 0, stream>>>(W1, W1t, 256);
    k_wt<<<64, 256, 0, stream>>>(W2, W2t, 64);

    k_agg1<<<(n + 7) / 8, 256, 0, stream>>>(xq, scale, off, pair, dinv, ax, n);

    dim3 g1((n + 63) / 64, 4);
    k_gemm<true><<<g1, 256, 0, stream>>>(ax, W1t, b1, h1, n, 256);
    dim3 g2((n + 63) / 64, 1);
    k_gemm<false><<<g2, 256, 0, stream>>>(h1, W2t, nullptr, tb, n, 64);
    k_quant2<<<(n * 8 + 255) / 256, 256, 0, stream>>>(tb, tq, tscale, n);

    k_agg2<<<(n + 31) / 32, 256, 0, stream>>>(tq, tscale, off, pair, dinv, b2, out, n);
}

// Round 6
// 559.915 us; speedup vs baseline: 2.5522x; 1.1581x over previous
//
#include <hip/hip_runtime.h>
#include <hip/hip_bf16.h>

// BasicGCN: out = log_softmax( A @ (relu(A @ x @ W1 + b1) @ W2) + b2 )
// A = sym-normalized adjacency with self-loops.
// Layer1 computed as (A@x)@W1 ; layer2 as A@(h1@W2) (64-dim aggregation).
// R6: atomic-free CSR build. Global atomicAdd throughput (~24 G/s, R5) made
// k_deg+k_csr ~220 us. New build: bucket edges by dst>>9 via per-block LDS
// histograms + tiny scans + LDS-ranked scatters. Zero global atomics.

typedef __bf16 bf16;
typedef bf16 bf16x8 __attribute__((ext_vector_type(8)));
typedef float f32x4 __attribute__((ext_vector_type(4)));
typedef signed char s8;
typedef signed char s8x8 __attribute__((ext_vector_type(8)));

#define NBLK 256  // edge-chunk blocks for bucketing passes

// ---------------- pass 1: per-block bucket histogram (LDS) ----------------
__global__ __launch_bounds__(256) void k_b1(const int* __restrict__ edge, int E, int chunk,
                                            int NB, int* __restrict__ gcnt) {
    __shared__ int cnt[512];
    int tid = threadIdx.x;
    for (int i = tid; i < NB; i += 256) cnt[i] = 0;
    __syncthreads();
    int s = blockIdx.x * chunk, e = min(s + chunk, E);
    for (int i = s + tid; i < e; i += 256) atomicAdd(&cnt[edge[E + i] >> 9], 1);
    __syncthreads();
    for (int i = tid; i < NB; i += 256) gcnt[blockIdx.x * NB + i] = cnt[i];
}

// ---------------- pass 2a: bucket starts (exclusive prefix of column sums) ----------------
__global__ void k_b2(const int* __restrict__ gcnt, int NB, int E, int* __restrict__ bstart) {
    __shared__ int col[256];
    int k = threadIdx.x;
    int sum = 0;
    if (k < NB)
        for (int b = 0; b < NBLK; ++b) sum += gcnt[b * NB + k];
    col[k] = sum;
    __syncthreads();
    for (int o = 1; o < 256; o <<= 1) {
        int v = (k >= o) ? col[k - o] : 0;
        __syncthreads();
        col[k] += v;
        __syncthreads();
    }
    if (k < NB) bstart[k] = col[k] - sum;
    if (k == 0) bstart[NB] = E;
}

// ---------------- pass 2b: per-(block,bucket) bases (column scans, in place) ----------------
__global__ void k_b2b(int* __restrict__ gcnt, int NB, const int* __restrict__ bstart) {
    __shared__ int col[256];
    int b = threadIdx.x;  // NBLK == 256
    int k = blockIdx.x;
    int v = gcnt[b * NB + k];
    col[b] = v;
    __syncthreads();
    for (int o = 1; o < 256; o <<= 1) {
        int t = (b >= o) ? col[b - o] : 0;
        __syncthreads();
        col[b] += t;
        __syncthreads();
    }
    gcnt[b * NB + k] = bstart[k] + col[b] - v;
}

// ---------------- pass 3: scatter edges into bucket-grouped ebuf ----------------
// packed: src (17 bits) | (dst & 511) << 17
__global__ __launch_bounds__(256) void k_b3(const int* __restrict__ edge, int E, int chunk,
                                            int NB, const int* __restrict__ base,
                                            int* __restrict__ ebuf) {
    __shared__ int cnt[512];
    __shared__ int bs[512];
    int tid = threadIdx.x;
    for (int i = tid; i < NB; i += 256) {
        cnt[i] = 0;
        bs[i] = base[blockIdx.x * NB + i];
    }
    __syncthreads();
    int s = blockIdx.x * chunk, e = min(s + chunk, E);
    for (int i = s + tid; i < e; i += 256) {
        int sv = edge[i], dv = edge[E + i];
        int k = dv >> 9;
        int r = atomicAdd(&cnt[k], 1);  // LDS atomic
        ebuf[bs[k] + r] = sv | ((dv & 511) << 17);
    }
}

// ---------------- pass 4: per-bucket degree histogram (LDS) -> dense deg ----------------
__global__ __launch_bounds__(256) void k_b4(const int* __restrict__ ebuf,
                                            const int* __restrict__ bstart, int n,
                                            int* __restrict__ deg) {
    __shared__ int cnt[512];
    int tid = threadIdx.x;
    int k = blockIdx.x;
    cnt[tid] = 0;
    cnt[tid + 256] = 0;
    __syncthreads();
    int s = bstart[k], e = bstart[k + 1];
    for (int i = s + tid; i < e; i += 256) atomicAdd(&cnt[(ebuf[i] >> 17) & 511], 1);
    __syncthreads();
    int base = k << 9;
    if (base + tid < n) deg[base + tid] = cnt[tid];
    if (base + 256 + tid < n) deg[base + 256 + tid] = cnt[tid + 256];
}

// ---------------- parallel scan over deg (3 tiny kernels, 1024-node chunks) ----------------
__global__ void k_scan1(const int* __restrict__ deg, int n, int* __restrict__ bsum) {
    __shared__ int red[256];
    int base = blockIdx.x * 1024;
    int tid = threadIdx.x;
    int s = 0;
#pragma unroll
    for (int j = 0; j < 4; ++j) {
        int i = base + j * 256 + tid;
        if (i < n) s += deg[i];
    }
    red[tid] = s;
    __syncthreads();
    for (int o = 128; o > 0; o >>= 1) {
        if (tid < o) red[tid] += red[tid + o];
        __syncthreads();
    }
    if (tid == 0) bsum[blockIdx.x] = red[0];
}

__global__ void k_scan2(int* __restrict__ bsum, int nb, int E, int* __restrict__ off, int n) {
    if (threadIdx.x == 0) {
        int run = 0;
        for (int b = 0; b < nb; ++b) { int v = bsum[b]; bsum[b] = run; run += v; }
        off[n] = E;
    }
}

__global__ void k_scan3(const int* __restrict__ deg, int n, const int* __restrict__ bbase,
                        int* __restrict__ off, float* __restrict__ dinv) {
    __shared__ int red[256];
    int base = blockIdx.x * 1024;
    int tid = threadIdx.x;
    int d[4], t = 0;
#pragma unroll
    for (int j = 0; j < 4; ++j) {
        int i = base + tid * 4 + j;
        d[j] = (i < n) ? deg[i] : 0;
        t += d[j];
    }
    red[tid] = t;
    __syncthreads();
    for (int o = 1; o < 256; o <<= 1) {
        int v = (tid >= o) ? red[tid - o] : 0;
        __syncthreads();
        red[tid] += v;
        __syncthreads();
    }
    int run = bbase[blockIdx.x] + red[tid] - t;  // exclusive prefix
#pragma unroll
    for (int j = 0; j < 4; ++j) {
        int i = base + tid * 4 + j;
        if (i < n) {
            off[i] = run;
            dinv[i] = rsqrtf((float)(d[j] + 1));  // +1 self-loop
            run += d[j];
        }
    }
}

// ---------------- pass 6: per-bucket CSR fill (LDS ranks, LDS off) ----------------
__global__ __launch_bounds__(256) void k_b6(const int* __restrict__ ebuf,
                                            const int* __restrict__ bstart,
                                            const int* __restrict__ off,
                                            const float* __restrict__ dinv, int n,
                                            int2* __restrict__ pair) {
    __shared__ int cnt[512];
    __shared__ int offl[512];
    int tid = threadIdx.x;
    int k = blockIdx.x;
    int base = k << 9;
    cnt[tid] = 0;
    cnt[tid + 256] = 0;
    offl[tid] = (base + tid < n) ? off[base + tid] : 0;
    offl[tid + 256] = (base + 256 + tid < n) ? off[base + 256 + tid] : 0;
    __syncthreads();
    int s = bstart[k], e = bstart[k + 1];
    for (int i = s + tid; i < e; i += 256) {
        int pk = ebuf[i];
        int sv = pk & 0x1ffff;
        int node = (pk >> 17) & 511;
        int r = atomicAdd(&cnt[node], 1);  // LDS atomic
        pair[offl[node] + r] = make_int2(sv, __float_as_int(dinv[sv]));
    }
}

// ---------------- x -> per-row-scaled int8 (one wave per row) ----------------
__global__ __launch_bounds__(256) void k_quant(const float* __restrict__ x,
                                               s8* __restrict__ xq,
                                               float* __restrict__ scale, int n) {
    int row = blockIdx.x * 4 + (threadIdx.x >> 6);
    int lane = threadIdx.x & 63;
    if (row >= n) return;
    f32x4 v = ((const f32x4*)x)[(size_t)row * 64 + lane];
    float m = fmaxf(fmaxf(fabsf(v[0]), fabsf(v[1])), fmaxf(fabsf(v[2]), fabsf(v[3])));
    for (int o = 32; o > 0; o >>= 1) m = fmaxf(m, __shfl_xor(m, o));
    m = fmaxf(m, 1e-20f);
    float inv = 127.0f / m;
    int b0 = __float2int_rn(v[0] * inv) & 255;
    int b1 = __float2int_rn(v[1] * inv) & 255;
    int b2 = __float2int_rn(v[2] * inv) & 255;
    int b3 = __float2int_rn(v[3] * inv) & 255;
    ((int*)xq)[(size_t)row * 64 + lane] = b0 | (b1 << 8) | (b2 << 16) | (b3 << 24);
    if (lane == 0) scale[row] = m / 127.0f;
}

// ---------------- tb (n x 64 bf16) -> per-row int8 + scale. 8 lanes/row ----------------
__global__ __launch_bounds__(256) void k_quant2(const bf16* __restrict__ tb,
                                                s8* __restrict__ tq,
                                                float* __restrict__ tscale, int n) {
    int t = blockIdx.x * 256 + threadIdx.x;
    int row = t >> 3;
    int l8 = t & 7;
    if (row >= n) return;
    bf16x8 v = ((const bf16x8*)tb)[(size_t)row * 8 + l8];
    float f[8], m = 0.0f;
#pragma unroll
    for (int j = 0; j < 8; ++j) { f[j] = (float)v[j]; m = fmaxf(m, fabsf(f[j])); }
    for (int o = 4; o > 0; o >>= 1) m = fmaxf(m, __shfl_xor(m, o));
    m = fmaxf(m, 1e-20f);
    float inv = 127.0f / m;
    int lo = 0, hi = 0;
#pragma unroll
    for (int j = 0; j < 4; ++j) lo |= (__float2int_rn(f[j] * inv) & 255) << (8 * j);
#pragma unroll
    for (int j = 0; j < 4; ++j) hi |= (__float2int_rn(f[4 + j] * inv) & 255) << (8 * j);
    ((int2*)tq)[(size_t)row * 8 + l8] = make_int2(lo, hi);
    if (l8 == 0) tscale[row] = m / 127.0f;
}

// ---------------- W (KxNC fp32) -> Wt (NCxK bf16) ----------------
__global__ void k_wt(const float* __restrict__ W, bf16* __restrict__ Wt, int NC) {
    int nc = blockIdx.x;
    int k = threadIdx.x;
    Wt[nc * 256 + k] = (bf16)W[k * NC + nc];
}

// ---------------- agg1: ax = A @ x (int8 table). 2 nodes/wave, 8B/lane, unroll 8 ----------------
__global__ __launch_bounds__(256) void k_agg1(const s8* __restrict__ xq,
                                              const float* __restrict__ scale,
                                              const int* __restrict__ off,
                                              const int2* __restrict__ pair,
                                              const float* __restrict__ dinv,
                                              bf16* __restrict__ ax, int n) {
    int wv = blockIdx.x * 4 + (threadIdx.x >> 6);
    int lane = threadIdx.x & 63;
    int node = wv * 2 + (lane >> 5);
    int l32 = lane & 31;
    if (node >= n) return;
    int s0 = off[node], s1 = off[node + 1];
    float dv = dinv[node];
    const s8x8* X = (const s8x8*)xq;
    s8x8 xs = X[(size_t)node * 32 + l32];
    float ws = dv * scale[node];
    float a[8];
#pragma unroll
    for (int j = 0; j < 8; ++j) a[j] = ws * (float)xs[j];
    int e = s0;
    for (; e + 8 <= s1; e += 8) {
        int2 p[8];
#pragma unroll
        for (int q = 0; q < 8; ++q) p[q] = pair[e + q];
        float sc[8];
#pragma unroll
        for (int q = 0; q < 8; ++q) sc[q] = scale[p[q].x];
        s8x8 t[8];
#pragma unroll
        for (int q = 0; q < 8; ++q) t[q] = X[(size_t)p[q].x * 32 + l32];
#pragma unroll
        for (int q = 0; q < 8; ++q) {
            float w = __int_as_float(p[q].y) * sc[q];
#pragma unroll
            for (int j = 0; j < 8; ++j) a[j] += w * (float)t[q][j];
        }
    }
    for (; e < s1; ++e) {
        int2 p = pair[e];
        float w = __int_as_float(p.y) * scale[p.x];
        s8x8 t = X[(size_t)p.x * 32 + l32];
#pragma unroll
        for (int j = 0; j < 8; ++j) a[j] += w * (float)t[j];
    }
    bf16x8 o;
#pragma unroll
    for (int j = 0; j < 8; ++j) o[j] = (bf16)(a[j] * dv);
    ((bf16x8*)ax)[(size_t)node * 32 + l32] = o;
}

// ---------------- bf16 MFMA GEMM: C[n x NC] = A[n x 256] @ Bt[NC x 256]^T ----------------
template <bool BIAS_RELU>
__global__ __launch_bounds__(256) void k_gemm(const bf16* __restrict__ A,
                                              const bf16* __restrict__ Bt,
                                              const float* __restrict__ bias,
                                              bf16* __restrict__ C, int n, int NC) {
    __shared__ __align__(16) bf16 As[4 * 64 * 8];
    __shared__ __align__(16) bf16 Bs[4 * 64 * 8];
    int tid = threadIdx.x;
    int bm = blockIdx.x * 64;
    int bn = blockIdx.y * 64;
    int w = tid >> 6, lane = tid & 63;
    int wm = w >> 1, wn = w & 1;

    int r = tid >> 2;
    int cq = tid & 3;
    int lds_idx = (((r >> 4) * 64) + cq * 16 + (r & 15)) * 8;
    int arow = bm + r; if (arow > n - 1) arow = n - 1;
    int brow = bn + r;

    f32x4 acc[2][2] = {};

    for (int k0 = 0; k0 < 256; k0 += 32) {
        __syncthreads();
        uint4 av = *(const uint4*)(A + (size_t)arow * 256 + k0 + cq * 8);
        uint4 bv = *(const uint4*)(Bt + (size_t)brow * 256 + k0 + cq * 8);
        *(uint4*)(As + lds_idx) = av;
        *(uint4*)(Bs + lds_idx) = bv;
        __syncthreads();
#pragma unroll
        for (int i = 0; i < 2; ++i) {
            bf16x8 af = *(const bf16x8*)(As + ((wm * 2 + i) * 64 + lane) * 8);
#pragma unroll
            for (int j = 0; j < 2; ++j) {
                bf16x8 bfr = *(const bf16x8*)(Bs + ((wn * 2 + j) * 64 + lane) * 8);
                acc[i][j] = __builtin_amdgcn_mfma_f32_16x16x32_bf16(af, bfr, acc[i][j], 0, 0, 0);
            }
        }
    }

    int colb = lane & 15, rowq = lane >> 4;
#pragma unroll
    for (int i = 0; i < 2; ++i) {
#pragma unroll
        for (int j = 0; j < 2; ++j) {
            int col = bn + wn * 32 + j * 16 + colb;
#pragma unroll
            for (int rr = 0; rr < 4; ++rr) {
                int row = bm + wm * 32 + i * 16 + rowq * 4 + rr;
                if (row < n) {
                    float v = acc[i][j][rr];
                    if constexpr (BIAS_RELU) {
                        v += bias[col];
                        v = v > 0.0f ? v : 0.0f;
                    }
                    C[(size_t)row * NC + col] = (bf16)v;
                }
            }
        }
    }
}

// ---------------- agg2 (int8 table) + bias + log_softmax. 8 nodes/wave, 8 lanes/row ----------------
__global__ __launch_bounds__(256) void k_agg2(const s8* __restrict__ tq,
                                              const float* __restrict__ tscale,
                                              const int* __restrict__ off,
                                              const int2* __restrict__ pair,
                                              const float* __restrict__ dinv,
                                              const float* __restrict__ b2,
                                              float* __restrict__ out, int n) {
    int wv = blockIdx.x * 4 + (threadIdx.x >> 6);
    int lane = threadIdx.x & 63;
    int node = wv * 8 + (lane >> 3);
    int l8 = lane & 7;
    if (node >= n) return;
    int s0 = off[node], s1 = off[node + 1];
    float dv = dinv[node];
    const s8x8* T = (const s8x8*)tq;  // row = 8 x s8x8 (64B)
    s8x8 ts = T[(size_t)node * 8 + l8];
    float ws = dv * tscale[node];
    float a[8];
#pragma unroll
    for (int j = 0; j < 8; ++j) a[j] = ws * (float)ts[j];
    int e = s0;
    for (; e + 4 <= s1; e += 4) {
        int2 p[4];
#pragma unroll
        for (int q = 0; q < 4; ++q) p[q] = pair[e + q];
        float sc[4];
#pragma unroll
        for (int q = 0; q < 4; ++q) sc[q] = tscale[p[q].x];
        s8x8 tv[4];
#pragma unroll
        for (int q = 0; q < 4; ++q) tv[q] = T[(size_t)p[q].x * 8 + l8];
#pragma unroll
        for (int q = 0; q < 4; ++q) {
            float w = __int_as_float(p[q].y) * sc[q];
#pragma unroll
            for (int j = 0; j < 8; ++j) a[j] += w * (float)tv[q][j];
        }
    }
    for (; e < s1; ++e) {
        int2 p = pair[e];
        float w = __int_as_float(p.y) * tscale[p.x];
        s8x8 tv = T[(size_t)p.x * 8 + l8];
#pragma unroll
        for (int j = 0; j < 8; ++j) a[j] += w * (float)tv[j];
    }
    const float4* B2 = (const float4*)b2;
    float4 bv0 = B2[l8 * 2], bv1 = B2[l8 * 2 + 1];
    a[0] = a[0] * dv + bv0.x; a[1] = a[1] * dv + bv0.y;
    a[2] = a[2] * dv + bv0.z; a[3] = a[3] * dv + bv0.w;
    a[4] = a[4] * dv + bv1.x; a[5] = a[5] * dv + bv1.y;
    a[6] = a[6] * dv + bv1.z; a[7] = a[7] * dv + bv1.w;
    float m = a[0];
#pragma unroll
    for (int j = 1; j < 8; ++j) m = fmaxf(m, a[j]);
    for (int o = 4; o > 0; o >>= 1) m = fmaxf(m, __shfl_xor(m, o));
    float s = 0.0f;
#pragma unroll
    for (int j = 0; j < 8; ++j) s += __expf(a[j] - m);
    for (int o = 4; o > 0; o >>= 1) s += __shfl_xor(s, o);
    float ls = m + __logf(s);
    f32x4 o0, o1;
    o0[0] = a[0] - ls; o0[1] = a[1] - ls; o0[2] = a[2] - ls; o0[3] = a[3] - ls;
    o1[0] = a[4] - ls; o1[1] = a[5] - ls; o1[2] = a[6] - ls; o1[3] = a[7] - ls;
    f32x4* O = (f32x4*)out;  // row = 16 x f32x4
    O[(size_t)node * 16 + l8 * 2] = o0;
    O[(size_t)node * 16 + l8 * 2 + 1] = o1;
}

extern "C" void kernel_launch(void* const* d_in, const int* in_sizes, int n_in,
                              void* d_out, int out_size, void* d_ws, size_t ws_size,
                              hipStream_t stream) {
    const float* x   = (const float*)d_in[0];
    const int*  edge = (const int*)d_in[1];
    const float* W1  = (const float*)d_in[2];
    const float* b1  = (const float*)d_in[3];
    const float* W2  = (const float*)d_in[4];
    const float* b2  = (const float*)d_in[5];
    float* out = (float*)d_out;

    int n = in_sizes[0] / 256;   // 100000
    int E = in_sizes[1] / 2;     // 3200000
    int nb = (n + 1023) / 1024;  // scan chunks
    int NB = (n + 511) >> 9;     // node buckets (512 nodes each); requires n < 131072
    int chunk = (E + NBLK - 1) / NBLK;

    char* ws = (char*)d_ws;
    auto alloc = [&](size_t bytes) -> char* {
        char* p = ws;
        ws += (bytes + 255) & ~(size_t)255;
        return p;
    };
    int*   gcnt   = (int*)alloc((size_t)NBLK * NB * 4);
    int*   bstart = (int*)alloc((size_t)(NB + 1) * 4);
    int*   ebuf   = (int*)alloc((size_t)E * 4);
    int*   deg    = (int*)alloc((size_t)n * 4);
    float* dinv   = (float*)alloc((size_t)n * 4);
    int*   off    = (int*)alloc((size_t)(n + 1) * 4);
    int*   bsum   = (int*)alloc((size_t)nb * 4);
    int2*  pair   = (int2*)alloc((size_t)E * 8);
    s8*    xq     = (s8*)alloc((size_t)n * 256);
    float* scale  = (float*)alloc((size_t)n * 4);
    bf16*  ax     = (bf16*)alloc((size_t)n * 256 * 2);
    bf16*  h1     = (bf16*)alloc((size_t)n * 256 * 2);
    bf16*  tb     = (bf16*)alloc((size_t)n * 64 * 2);
    s8*    tq     = (s8*)alloc((size_t)n * 64);
    float* tscale = (float*)alloc((size_t)n * 4);
    bf16*  W1t    = (bf16*)alloc(256 * 256 * 2);
    bf16*  W2t    = (bf16*)alloc(64 * 256 * 2);

    // --- CSR build (no global atomics) ---
    k_b1<<<NBLK, 256, 0, stream>>>(edge, E, chunk, NB, gcnt);
    k_b2<<<1, 256, 0, stream>>>(gcnt, NB, E, bstart);
    k_b2b<<<NB, 256, 0, stream>>>(gcnt, NB, bstart);
    k_b3<<<NBLK, 256, 0, stream>>>(edge, E, chunk, NB, gcnt, ebuf);
    k_b4<<<NB, 256, 0, stream>>>(ebuf, bstart, n, deg);
    k_scan1<<<nb, 256, 0, stream>>>(deg, n, bsum);
    k_scan2<<<1, 64, 0, stream>>>(bsum, nb, E, off, n);
    k_scan3<<<nb, 256, 0, stream>>>(deg, n, bsum, off, dinv);
    k_b6<<<NB, 256, 0, stream>>>(ebuf, bstart, off, dinv, n, pair);

    // --- feature prep ---
    k_quant<<<(n + 3) / 4, 256, 0, stream>>>(x, xq, scale, n);
    k_wt<<<256, 256, 0, stream>>>(W1, W1t, 256);
    k_wt<<<64, 256, 0, stream>>>(W2, W2t, 64);

    // --- layer 1 ---
    k_agg1<<<(n + 7) / 8, 256, 0, stream>>>(xq, scale, off, pair, dinv, ax, n);
    dim3 g1((n + 63) / 64, 4);
    k_gemm<true><<<g1, 256, 0, stream>>>(ax, W1t, b1, h1, n, 256);

    // --- layer 2 ---
    dim3 g2((n + 63) / 64, 1);
    k_gemm<false><<<g2, 256, 0, stream>>>(h1, W2t, nullptr, tb, n, 64);
    k_quant2<<<(n * 8 + 255) / 256, 256, 0, stream>>>(tb, tq, tscale, n);
    k_agg2<<<(n + 31) / 32, 256, 0, stream>>>(tq, tscale, off, pair, dinv, b2, out, n);
}